// Round 7
// baseline (1201.132 us; speedup 1.0000x reference)
//
#include <hip/hip_runtime.h>
#include <hip/hip_bf16.h>

#define T_LEN 1024
#define D_DIM 1024
#define V_DIM 17
#define H_NUM 16
#define DH_DIM 64
#define F_DIM 4096
#define R_LORA 32
#define N_LAYERS 2
#define N_STEPS 2
#define MASK_ID 16
#define LORA_SCALE 2.0f

typedef __attribute__((ext_vector_type(8))) short bfx8;   // 8 bf16 in 4 VGPRs
typedef __attribute__((ext_vector_type(4))) float f32x4;

typedef unsigned short ushort_t;
typedef unsigned int uint_t;

#define AS1 __attribute__((address_space(1)))
#define AS3 __attribute__((address_space(3)))

__device__ __forceinline__ void gload16(const ushort_t* g, ushort_t* l) {
    __builtin_amdgcn_global_load_lds((const AS1 void*)(const void*)g,
                                     (AS3 void*)(void*)l, 16, 0, 0);
}

__device__ __forceinline__ ushort_t f2bf(float v) {
    __hip_bfloat16 h = __float2bfloat16(v);
    return __builtin_bit_cast(unsigned short, h);
}
__device__ __forceinline__ float bf2f(ushort_t u) {
    return __uint_as_float(((uint_t)u) << 16);
}
__device__ __forceinline__ void split4_store(float y0, float y1, float y2, float y3,
                                             ushort_t* __restrict__ hi, ushort_t* __restrict__ lo,
                                             size_t idx) {
    ushort_t h0 = f2bf(y0), h1 = f2bf(y1), h2 = f2bf(y2), h3 = f2bf(y3);
    ushort_t l0 = f2bf(y0 - bf2f(h0));
    ushort_t l1 = f2bf(y1 - bf2f(h1));
    ushort_t l2 = f2bf(y2 - bf2f(h2));
    ushort_t l3 = f2bf(y3 - bf2f(h3));
    uint2 hv, lv;
    hv.x = (uint_t)h0 | ((uint_t)h1 << 16);
    hv.y = (uint_t)h2 | ((uint_t)h3 << 16);
    lv.x = (uint_t)l0 | ((uint_t)l1 << 16);
    lv.y = (uint_t)l2 | ((uint_t)l3 << 16);
    *(uint2*)(hi + idx) = hv;
    *(uint2*)(lo + idx) = lv;
}

// ---------------- init soft ----------------
__global__ void init_soft_kernel(float* __restrict__ soft) {
    int idx = blockIdx.x * blockDim.x + threadIdx.x;
    if (idx < T_LEN * V_DIM) {
        soft[idx] = ((idx % V_DIM) == MASK_ID) ? 1.0f : 0.0f;
    }
}

// ---------------- fused embed + rms + split ----------------
__global__ __launch_bounds__(256) void embed_rms_split_kernel(
    const float* __restrict__ soft, const float* __restrict__ E,
    const float* __restrict__ w, float* __restrict__ x,
    ushort_t* __restrict__ hi, ushort_t* __restrict__ lo)
{
    const int t = blockIdx.x, tid = threadIdx.x;
    __shared__ float srow[V_DIM];
    __shared__ float red[4];
    if (tid < V_DIM) srow[tid] = soft[t * V_DIM + tid];
    __syncthreads();
    const int d0 = tid * 4;
    float4 acc = {0.f, 0.f, 0.f, 0.f};
    #pragma unroll
    for (int v = 0; v < V_DIM; v++) {
        float s = srow[v];
        float4 e = *(const float4*)(E + (size_t)v * D_DIM + d0);
        acc.x = fmaf(s, e.x, acc.x);
        acc.y = fmaf(s, e.y, acc.y);
        acc.z = fmaf(s, e.z, acc.z);
        acc.w = fmaf(s, e.w, acc.w);
    }
    size_t base = (size_t)t * D_DIM + d0;
    *(float4*)(x + base) = acc;
    float ss = acc.x * acc.x + acc.y * acc.y + acc.z * acc.z + acc.w * acc.w;
    const int lane = tid & 63, wv = tid >> 6;
    #pragma unroll
    for (int off = 32; off > 0; off >>= 1) ss += __shfl_xor(ss, off);
    if (lane == 0) red[wv] = ss;
    __syncthreads();
    ss = red[0] + red[1] + red[2] + red[3];
    const float r = 1.0f / sqrtf(ss * (1.0f / D_DIM) + 1e-6f);
    const float4 wv4 = *(const float4*)(w + d0);
    split4_store(acc.x * r * wv4.x, acc.y * r * wv4.y, acc.z * r * wv4.z, acc.w * r * wv4.w,
                 hi, lo, base);
}

// ---------------- fold v3: out^T = split(W + 2*A@B) ----------------
__global__ __launch_bounds__(256) void fold_kernel(
    const float* __restrict__ W,   // [L,K,N]
    const float* __restrict__ A,   // [L,K,R]
    const float* __restrict__ Bm,  // [L,R,N]
    ushort_t* __restrict__ oHi,    // [L,N,K]
    ushort_t* __restrict__ oLo,
    int K, int N)
{
    const int l = blockIdx.z;
    W   += (size_t)l * K * N;
    A   += (size_t)l * K * R_LORA;
    Bm  += (size_t)l * R_LORA * N;
    oHi += (size_t)l * K * N;
    oLo += (size_t)l * K * N;
    __shared__ float Als[64][R_LORA + 1];
    __shared__ uint_t tile[64][65];
    const int tid = threadIdx.x;
    const int n0 = blockIdx.x * 64, k0 = blockIdx.y * 64;

    {
        const int row = tid >> 2, c0 = (tid & 3) * 8;
        const float* src = A + (size_t)(k0 + row) * R_LORA + c0;
        float4 a0 = *(const float4*)(src);
        float4 a1 = *(const float4*)(src + 4);
        Als[row][c0 + 0] = a0.x; Als[row][c0 + 1] = a0.y;
        Als[row][c0 + 2] = a0.z; Als[row][c0 + 3] = a0.w;
        Als[row][c0 + 4] = a1.x; Als[row][c0 + 5] = a1.y;
        Als[row][c0 + 6] = a1.z; Als[row][c0 + 7] = a1.w;
    }
    const int nl = tid & 63, kq = tid >> 6;
    float wreg[16];
    #pragma unroll
    for (int i = 0; i < 16; i++)
        wreg[i] = W[(size_t)(k0 + kq * 16 + i) * N + n0 + nl];
    float breg[R_LORA];
    #pragma unroll
    for (int r = 0; r < R_LORA; r++) breg[r] = Bm[(size_t)r * N + n0 + nl];
    __syncthreads();
    #pragma unroll
    for (int i = 0; i < 16; i++) {
        const int kl = kq * 16 + i;
        float acc = 0.f;
        #pragma unroll
        for (int r = 0; r < R_LORA; r++) acc = fmaf(Als[kl][r], breg[r], acc);
        float val = wreg[i] + LORA_SCALE * acc;
        ushort_t h = f2bf(val);
        tile[kl][nl] = ((uint_t)h << 16) | (uint_t)f2bf(val - bf2f(h));
    }
    __syncthreads();
    {
        const int nl2 = tid >> 2;
        const int kc0 = (tid & 3) * 16;
        ushort_t hb[16], lb[16];
        #pragma unroll
        for (int i = 0; i < 16; i++) {
            uint_t pk = tile[kc0 + i][nl2];
            hb[i] = (ushort_t)(pk >> 16);
            lb[i] = (ushort_t)(pk & 0xffffu);
        }
        size_t idx = (size_t)(n0 + nl2) * K + k0 + kc0;
        *(uint4*)(oHi + idx)     = *(uint4*)&hb[0];
        *(uint4*)(oHi + idx + 8) = *(uint4*)&hb[8];
        *(uint4*)(oLo + idx)     = *(uint4*)&lb[0];
        *(uint4*)(oLo + idx + 8) = *(uint4*)&lb[8];
    }
}

// ---------------- 128x128 MFMA split-bf16 GEMM with jobs x kslices ----------------
struct GemmJob {
    const ushort_t* Bh;
    const ushort_t* Bl;
    float* Cf;        // if non-null: f32 store (partials: slot s at Cf + s*T_LEN*N)
    ushort_t* Ch;     // else split store (kslices must be 1)
    ushort_t* Cl;
    int k0, k1;
};

__global__ __launch_bounds__(256) void gemm128_kernel(
    const ushort_t* __restrict__ Ahi, const ushort_t* __restrict__ Alo,
    int K, int N, int kslices,
    GemmJob j0, GemmJob j1, GemmJob j2, GemmJob j3,
    GemmJob j4, GemmJob j5, GemmJob j6, GemmJob j7)
{
    GemmJob jb;
    int s;
    {
        const int z = blockIdx.z;
        const int ji = z / kslices;
        s = z - ji * kslices;
        if      (ji == 0) jb = j0; else if (ji == 1) jb = j1;
        else if (ji == 2) jb = j2; else if (ji == 3) jb = j3;
        else if (ji == 4) jb = j4; else if (ji == 5) jb = j5;
        else if (ji == 6) jb = j6; else jb = j7;
    }
    const int klen = (jb.k1 - jb.k0) / kslices;
    const int myk0 = jb.k0 + s * klen;
    const int myk1 = myk0 + klen;
    float* Cf = jb.Cf ? jb.Cf + (size_t)s * T_LEN * (size_t)N : nullptr;

    __shared__ ushort_t Ash[128][32];
    __shared__ ushort_t Asl[128][32];
    __shared__ ushort_t Bsh[128][32];
    __shared__ ushort_t Bsl[128][32];

    const int tid = threadIdx.x, lane = tid & 63, w = tid >> 6;
    const int l15 = lane & 15, lg = lane >> 4;
    const int m0 = blockIdx.y * 128, n0 = blockIdx.x * 128;
    const int wm = (w >> 1) * 64, wn = (w & 1) * 64;

    const int r0 = w * 32;
    const int rsub = lane >> 2;
    const int cs = lane & 3;
    const int csl = (cs ^ ((rsub >> 1) & 3)) * 8;   // pre-swizzled source col (shorts)
    const int rsl = (lg ^ ((l15 >> 1) & 3)) * 8;    // swizzled read col (shorts)

    f32x4 acc[4][4];
    #pragma unroll
    for (int i = 0; i < 4; i++)
        #pragma unroll
        for (int j = 0; j < 4; j++) acc[i][j] = f32x4{0.f, 0.f, 0.f, 0.f};

    const size_t rowA = (size_t)(m0 + r0 + rsub) * K;
    const size_t rowB = (size_t)(n0 + r0 + rsub) * K;
    const size_t rstep = (size_t)16 * K;

    for (int kk = myk0; kk < myk1; kk += 32) {
        {
            const ushort_t* a0 = Ahi + rowA + kk + csl;
            const ushort_t* a1 = Alo + rowA + kk + csl;
            const ushort_t* b0 = jb.Bh + rowB + kk + csl;
            const ushort_t* b1 = jb.Bl + rowB + kk + csl;
            gload16(a0,         &Ash[r0][0]);
            gload16(a0 + rstep, &Ash[r0 + 16][0]);
            gload16(a1,         &Asl[r0][0]);
            gload16(a1 + rstep, &Asl[r0 + 16][0]);
            gload16(b0,         &Bsh[r0][0]);
            gload16(b0 + rstep, &Bsh[r0 + 16][0]);
            gload16(b1,         &Bsl[r0][0]);
            gload16(b1 + rstep, &Bsl[r0 + 16][0]);
        }
        __syncthreads();
        bfx8 bh[4], bl[4];
        #pragma unroll
        for (int ni = 0; ni < 4; ni++) {
            bh[ni] = *(const bfx8*)&Bsh[wn + ni * 16 + l15][rsl];
            bl[ni] = *(const bfx8*)&Bsl[wn + ni * 16 + l15][rsl];
        }
        #pragma unroll
        for (int mi = 0; mi < 4; mi++) {
            bfx8 ah = *(const bfx8*)&Ash[wm + mi * 16 + l15][rsl];
            bfx8 al = *(const bfx8*)&Asl[wm + mi * 16 + l15][rsl];
            #pragma unroll
            for (int ni = 0; ni < 4; ni++) {
                acc[mi][ni] = __builtin_amdgcn_mfma_f32_16x16x32_bf16(ah, bh[ni], acc[mi][ni], 0, 0, 0);
                acc[mi][ni] = __builtin_amdgcn_mfma_f32_16x16x32_bf16(ah, bl[ni], acc[mi][ni], 0, 0, 0);
                acc[mi][ni] = __builtin_amdgcn_mfma_f32_16x16x32_bf16(al, bh[ni], acc[mi][ni], 0, 0, 0);
            }
        }
        __syncthreads();
    }

    if (Cf) {
        #pragma unroll
        for (int mi = 0; mi < 4; mi++)
            #pragma unroll
            for (int ni = 0; ni < 4; ni++) {
                int col = n0 + wn + ni * 16 + l15;
                #pragma unroll
                for (int i = 0; i < 4; i++) {
                    int row = m0 + wm + mi * 16 + lg * 4 + i;
                    Cf[(size_t)row * N + col] = acc[mi][ni][i];
                }
            }
    } else {
        #pragma unroll
        for (int mi = 0; mi < 4; mi++)
            #pragma unroll
            for (int ni = 0; ni < 4; ni++) {
                int col = n0 + wn + ni * 16 + l15;
                #pragma unroll
                for (int i = 0; i < 4; i++) {
                    int row = m0 + wm + mi * 16 + lg * 4 + i;
                    size_t idx = (size_t)row * N + col;
                    float v = acc[mi][ni][i];
                    ushort_t h = f2bf(v);
                    jb.Ch[idx] = h;
                    jb.Cl[idx] = f2bf(v - bf2f(h));
                }
            }
    }
}

// ---------------- qkv epilogue: q/k/v = split(sum of S partials each) ----------------
__global__ __launch_bounds__(256) void qkv_sum_split_kernel(
    const float* __restrict__ P, int S,
    ushort_t* __restrict__ qbh, ushort_t* __restrict__ qbl,
    ushort_t* __restrict__ kbh, ushort_t* __restrict__ kbl,
    ushort_t* __restrict__ vbh, ushort_t* __restrict__ vbl)
{
    const size_t DD1 = (size_t)T_LEN * D_DIM;
    size_t e = ((size_t)blockIdx.x * 256 + threadIdx.x) * 4;
    float4 q = {0,0,0,0}, k = {0,0,0,0}, v = {0,0,0,0};
    for (int j = 0; j < S; j++) {
        float4 a = *(const float4*)(P + (size_t)j * DD1 + e);
        q.x += a.x; q.y += a.y; q.z += a.z; q.w += a.w;
        float4 b = *(const float4*)(P + (size_t)(S + j) * DD1 + e);
        k.x += b.x; k.y += b.y; k.z += b.z; k.w += b.w;
        float4 c = *(const float4*)(P + (size_t)(2 * S + j) * DD1 + e);
        v.x += c.x; v.y += c.y; v.z += c.z; v.w += c.w;
    }
    split4_store(q.x, q.y, q.z, q.w, qbh, qbl, e);
    split4_store(k.x, k.y, k.z, k.w, kbh, kbl, e);
    split4_store(v.x, v.y, v.z, v.w, vbh, vbl, e);
}

// ---------------- x += sum of nparts DD-sized partials ----------------
__global__ void addn_kernel(float* __restrict__ x, const float* __restrict__ P,
                            int nparts, int n4) {
    int i = blockIdx.x * blockDim.x + threadIdx.x;
    if (i < n4) {
        const size_t DD1 = (size_t)T_LEN * D_DIM;
        size_t e = (size_t)i * 4;
        float4 xv = *(const float4*)(x + e);
        for (int j = 0; j < nparts; j++) {
            float4 p = *(const float4*)(P + (size_t)j * DD1 + e);
            xv.x += p.x; xv.y += p.y; xv.z += p.z; xv.w += p.w;
        }
        *(float4*)(x + e) = xv;
    }
}

// ---------------- fused: x += sum(nparts); h = split(rms(x,w)) ----------------
__global__ __launch_bounds__(256) void add_rms_split_kernel(
    float* __restrict__ x, const float* __restrict__ P, int nparts,
    const float* __restrict__ w, ushort_t* __restrict__ hi, ushort_t* __restrict__ lo)
{
    const int t = blockIdx.x, tid = threadIdx.x;
    const size_t DD1 = (size_t)T_LEN * D_DIM;
    size_t base = (size_t)t * D_DIM + tid * 4;
    float4 xv = *(const float4*)(x + base);
    for (int j = 0; j < nparts; j++) {
        float4 p = *(const float4*)(P + (size_t)j * DD1 + base);
        xv.x += p.x; xv.y += p.y; xv.z += p.z; xv.w += p.w;
    }
    *(float4*)(x + base) = xv;
    float ss = xv.x * xv.x + xv.y * xv.y + xv.z * xv.z + xv.w * xv.w;
    __shared__ float red[4];
    const int lane = tid & 63, wv = tid >> 6;
    #pragma unroll
    for (int off = 32; off > 0; off >>= 1) ss += __shfl_xor(ss, off);
    if (lane == 0) red[wv] = ss;
    __syncthreads();
    ss = red[0] + red[1] + red[2] + red[3];
    const float r = 1.0f / sqrtf(ss * (1.0f / D_DIM) + 1e-6f);
    const float4 wv4 = *(const float4*)(w + tid * 4);
    split4_store(xv.x * r * wv4.x, xv.y * r * wv4.y, xv.z * r * wv4.z, xv.w * r * wv4.w,
                 hi, lo, base);
}

// ---------------- silu epilogue: ff = silu(sum g-parts)*(sum u-parts) -> split ----------------
// g parts at P[0..parts), u parts at P[parts..2*parts), each DF-sized
__global__ void silu_sum_split_kernel(const float* __restrict__ P, int parts,
                                      ushort_t* __restrict__ hi, ushort_t* __restrict__ lo) {
    const size_t DF1 = (size_t)T_LEN * F_DIM;
    size_t e = ((size_t)blockIdx.x * 256 + threadIdx.x) * 4;
    float4 g = {0,0,0,0}, u = {0,0,0,0};
    for (int j = 0; j < parts; j++) {
        float4 a = *(const float4*)(P + (size_t)j * DF1 + e);
        g.x += a.x; g.y += a.y; g.z += a.z; g.w += a.w;
        float4 b = *(const float4*)(P + (size_t)(parts + j) * DF1 + e);
        u.x += b.x; u.y += b.y; u.z += b.z; u.w += b.w;
    }
    float y0 = g.x / (1.f + expf(-g.x)) * u.x;
    float y1 = g.y / (1.f + expf(-g.y)) * u.y;
    float y2 = g.z / (1.f + expf(-g.z)) * u.z;
    float y3 = g.w / (1.f + expf(-g.w)) * u.w;
    split4_store(y0, y1, y2, y3, hi, lo, e);
}

// ---------------- MFMA flash attention ----------------
#define KS_PAD 72
#define P_PAD 72
__global__ __launch_bounds__(256, 1) void attn_mfma_kernel(
    const ushort_t* __restrict__ qh, const ushort_t* __restrict__ ql,
    const ushort_t* __restrict__ kh, const ushort_t* __restrict__ kl,
    const ushort_t* __restrict__ vh, const ushort_t* __restrict__ vl,
    ushort_t* __restrict__ chi, ushort_t* __restrict__ clo)
{
    __shared__ ushort_t Ksh[64][KS_PAD];
    __shared__ ushort_t Ksl[64][KS_PAD];
    __shared__ ushort_t VTh[64][KS_PAD];
    __shared__ ushort_t VTl[64][KS_PAD];
    __shared__ ushort_t Ph[4][16][P_PAD];
    __shared__ ushort_t Pl[4][16][P_PAD];

    const int qt = blockIdx.x, hh = blockIdx.y;
    const int tid = threadIdx.x, w = tid >> 6, lane = tid & 63;
    const int l15 = lane & 15, lg = lane >> 4;
    const int q0 = qt * 64;
    const int hcol = hh * DH_DIM;

    bfx8 qa_h[2], qa_l[2];
    {
        size_t qrow = (size_t)(q0 + w * 16 + l15) * D_DIM + hcol;
        #pragma unroll
        for (int ks = 0; ks < 2; ks++) {
            qa_h[ks] = *(const bfx8*)(qh + qrow + ks * 32 + lg * 8);
            qa_l[ks] = *(const bfx8*)(ql + qrow + ks * 32 + lg * 8);
        }
    }

    f32x4 o[4];
    #pragma unroll
    for (int ni = 0; ni < 4; ni++) o[ni] = f32x4{0.f, 0.f, 0.f, 0.f};
    float mrun[4], lrun[4];
    #pragma unroll
    for (int i = 0; i < 4; i++) { mrun[i] = -3.0e38f; lrun[i] = 0.f; }

    const int srow = tid >> 2;
    const int sseg = (tid & 3) * 16;
    const int vp = tid & 31;
    const int vd0 = (tid >> 5) * 8;

    for (int kt = 0; kt <= qt; kt++) {
        __syncthreads();
        {
            size_t src = (size_t)(kt * 64 + srow) * D_DIM + hcol + sseg;
            *(uint4*)&Ksh[srow][sseg]     = *(const uint4*)(kh + src);
            *(uint4*)&Ksh[srow][sseg + 8] = *(const uint4*)(kh + src + 8);
            *(uint4*)&Ksl[srow][sseg]     = *(const uint4*)(kl + src);
            *(uint4*)&Ksl[srow][sseg + 8] = *(const uint4*)(kl + src + 8);
        }
        {
            size_t s0 = (size_t)(kt * 64 + 2 * vp) * D_DIM + hcol + vd0;
            uint4 h0 = *(const uint4*)(vh + s0);
            uint4 h1 = *(const uint4*)(vh + s0 + D_DIM);
            uint4 l0 = *(const uint4*)(vl + s0);
            uint4 l1 = *(const uint4*)(vl + s0 + D_DIM);
            const ushort_t* a = (const ushort_t*)&h0;
            const ushort_t* b = (const ushort_t*)&h1;
            const ushort_t* c = (const ushort_t*)&l0;
            const ushort_t* d = (const ushort_t*)&l1;
            #pragma unroll
            for (int j = 0; j < 8; j++) {
                *(uint_t*)&VTh[vd0 + j][2 * vp] = (uint_t)a[j] | ((uint_t)b[j] << 16);
                *(uint_t*)&VTl[vd0 + j][2 * vp] = (uint_t)c[j] | ((uint_t)d[j] << 16);
            }
        }
        __syncthreads();

        f32x4 s[4];
        #pragma unroll
        for (int ni = 0; ni < 4; ni++) s[ni] = f32x4{0.f, 0.f, 0.f, 0.f};
        #pragma unroll
        for (int ks = 0; ks < 2; ks++) {
            #pragma unroll
            for (int ni = 0; ni < 4; ni++) {
                bfx8 bh = *(const bfx8*)&Ksh[ni * 16 + l15][ks * 32 + lg * 8];
                bfx8 bl = *(const bfx8*)&Ksl[ni * 16 + l15][ks * 32 + lg * 8];
                s[ni] = __builtin_amdgcn_mfma_f32_16x16x32_bf16(qa_h[ks], bh, s[ni], 0, 0, 0);
                s[ni] = __builtin_amdgcn_mfma_f32_16x16x32_bf16(qa_h[ks], bl, s[ni], 0, 0, 0);
                s[ni] = __builtin_amdgcn_mfma_f32_16x16x32_bf16(qa_l[ks], bh, s[ni], 0, 0, 0);
            }
        }

        const int kbase = kt * 64;
        float rmax[4];
        #pragma unroll
        for (int i = 0; i < 4; i++) rmax[i] = -3.0e38f;
        #pragma unroll
        for (int ni = 0; ni < 4; ni++) {
            int kc = kbase + ni * 16 + l15;
            #pragma unroll
            for (int i = 0; i < 4; i++) {
                int qrow = q0 + w * 16 + lg * 4 + i;
                float v = s[ni][i] * 0.125f;
                v = (kc <= qrow) ? v : -3.0e38f;
                s[ni][i] = v;
                rmax[i] = fmaxf(rmax[i], v);
            }
        }
        #pragma unroll
        for (int off = 1; off < 16; off <<= 1) {
            #pragma unroll
            for (int i = 0; i < 4; i++) rmax[i] = fmaxf(rmax[i], __shfl_xor(rmax[i], off));
        }
        float psum[4];
        #pragma unroll
        for (int i = 0; i < 4; i++) {
            float nm = fmaxf(mrun[i], rmax[i]);
            float sc = __expf(mrun[i] - nm);
            lrun[i] *= sc;
            #pragma unroll
            for (int ni = 0; ni < 4; ni++) o[ni][i] *= sc;
            mrun[i] = nm;
            psum[i] = 0.f;
        }
        #pragma unroll
        for (int ni = 0; ni < 4; ni++) {
            #pragma unroll
            for (int i = 0; i < 4; i++) {
                float e = __expf(s[ni][i] - mrun[i]);
                s[ni][i] = e;
                psum[i] += e;
            }
        }
        #pragma unroll
        for (int off = 1; off < 16; off <<= 1) {
            #pragma unroll
            for (int i = 0; i < 4; i++) psum[i] += __shfl_xor(psum[i], off);
        }
        #pragma unroll
        for (int i = 0; i < 4; i++) lrun[i] += psum[i];

        #pragma unroll
        for (int ni = 0; ni < 4; ni++) {
            #pragma unroll
            for (int i = 0; i < 4; i++) {
                float e = s[ni][i];
                ushort_t hp = f2bf(e);
                Ph[w][lg * 4 + i][ni * 16 + l15] = hp;
                Pl[w][lg * 4 + i][ni * 16 + l15] = f2bf(e - bf2f(hp));
            }
        }
        #pragma unroll
        for (int ks = 0; ks < 2; ks++) {
            bfx8 ah = *(const bfx8*)&Ph[w][l15][ks * 32 + lg * 8];
            bfx8 al = *(const bfx8*)&Pl[w][l15][ks * 32 + lg * 8];
            #pragma unroll
            for (int ni = 0; ni < 4; ni++) {
                bfx8 bh = *(const bfx8*)&VTh[ni * 16 + l15][ks * 32 + lg * 8];
                bfx8 bl = *(const bfx8*)&VTl[ni * 16 + l15][ks * 32 + lg * 8];
                o[ni] = __builtin_amdgcn_mfma_f32_16x16x32_bf16(ah, bh, o[ni], 0, 0, 0);
                o[ni] = __builtin_amdgcn_mfma_f32_16x16x32_bf16(ah, bl, o[ni], 0, 0, 0);
                o[ni] = __builtin_amdgcn_mfma_f32_16x16x32_bf16(al, bh, o[ni], 0, 0, 0);
            }
        }
    }

    #pragma unroll
    for (int i = 0; i < 4; i++) {
        float inv = 1.0f / lrun[i];
        #pragma unroll
        for (int ni = 0; ni < 4; ni++) o[ni][i] *= inv;
    }
    #pragma unroll
    for (int ni = 0; ni < 4; ni++) {
        int col = hcol + ni * 16 + l15;
        #pragma unroll
        for (int i = 0; i < 4; i++) {
            int row = q0 + w * 16 + lg * 4 + i;
            size_t idx = (size_t)row * D_DIM + col;
            float v = o[ni][i];
            ushort_t hp = f2bf(v);
            chi[idx] = hp;
            clo[idx] = f2bf(v - bf2f(hp));
        }
    }
}

// ---------------- head ----------------
__global__ __launch_bounds__(256) void head_kernel(const float* __restrict__ x,
                                                   const float* __restrict__ lnf,
                                                   const float* __restrict__ E,
                                                   const int* __restrict__ tok,
                                                   float* __restrict__ soft) {
    int t = blockIdx.x;
    int tid = threadIdx.x;
    __shared__ float y[D_DIM];
    __shared__ float red[4];
    __shared__ float logits[V_DIM];
    const float* xr = x + (size_t)t * D_DIM;
    float ss = 0.f;
    for (int d = tid; d < D_DIM; d += 256) { float v = xr[d]; ss += v * v; }
    int lane = tid & 63, wave = tid >> 6;
    for (int off = 32; off > 0; off >>= 1) ss += __shfl_xor(ss, off);
    if (lane == 0) red[wave] = ss;
    __syncthreads();
    ss = red[0] + red[1] + red[2] + red[3];
    float r = 1.0f / sqrtf(ss * (1.0f / D_DIM) + 1e-6f);
    for (int d = tid; d < D_DIM; d += 256) y[d] = xr[d] * r * lnf[d];
    __syncthreads();
    for (int vv = wave; vv < V_DIM; vv += 4) {
        float p = 0.f;
        for (int d = lane; d < D_DIM; d += 64) p += y[d] * E[vv * D_DIM + d];
        for (int off = 32; off > 0; off >>= 1) p += __shfl_xor(p, off);
        if (lane == 0) logits[vv] = p;
    }
    __syncthreads();
    if (tid == 0) {
        int tk = tok[t];
        if (tk != MASK_ID) {
            for (int vv = 0; vv < V_DIM; vv++) soft[t * V_DIM + vv] = (vv == tk) ? 1.f : 0.f;
        } else {
            float mx = -1e30f;
            for (int vv = 0; vv < V_DIM; vv++) mx = fmaxf(mx, logits[vv]);
            float sm = 0.f;
            float e[V_DIM];
            for (int vv = 0; vv < V_DIM; vv++) { e[vv] = expf(logits[vv] - mx); sm += e[vv]; }
            float invs = 1.0f / sm;
            for (int vv = 0; vv < V_DIM; vv++) soft[t * V_DIM + vv] = e[vv] * invs;
        }
    }
}

// ---------------- argmax ----------------
__global__ void argmax_kernel(const float* __restrict__ soft, int* __restrict__ out) {
    int t = blockIdx.x * blockDim.x + threadIdx.x;
    if (t < T_LEN) {
        const float* s = soft + t * V_DIM;
        int best = 0;
        float bv = s[0];
        #pragma unroll
        for (int vv = 1; vv < V_DIM; vv++) {
            float v = s[vv];
            if (v > bv) { bv = v; best = vv; }
        }
        out[t] = best;
    }
}

// ================= fallback kernels (fp32, if ws too small) =================
__global__ __launch_bounds__(256) void rms_kernel(const float* __restrict__ x,
                                                  const float* __restrict__ w,
                                                  float* __restrict__ out) {
    int t = blockIdx.x;
    const float* xr = x + (size_t)t * D_DIM;
    float ss = 0.f;
    for (int d = threadIdx.x; d < D_DIM; d += 256) { float v = xr[d]; ss += v * v; }
    __shared__ float red[4];
    int lane = threadIdx.x & 63, wave = threadIdx.x >> 6;
    for (int off = 32; off > 0; off >>= 1) ss += __shfl_xor(ss, off);
    if (lane == 0) red[wave] = ss;
    __syncthreads();
    ss = red[0] + red[1] + red[2] + red[3];
    float r = 1.0f / sqrtf(ss * (1.0f / D_DIM) + 1e-6f);
    for (int d = threadIdx.x; d < D_DIM; d += 256) out[(size_t)t * D_DIM + d] = xr[d] * r * w[d];
}

__global__ __launch_bounds__(256) void embed_kernel(const float* __restrict__ soft,
                                                    const float* __restrict__ E,
                                                    float* __restrict__ x) {
    int t = blockIdx.x;
    __shared__ float srow[V_DIM];
    if (threadIdx.x < V_DIM) srow[threadIdx.x] = soft[t * V_DIM + threadIdx.x];
    __syncthreads();
    for (int d = threadIdx.x; d < D_DIM; d += 256) {
        float acc = 0.f;
        #pragma unroll
        for (int v = 0; v < V_DIM; v++) acc += srow[v] * E[v * D_DIM + d];
        x[(size_t)t * D_DIM + d] = acc;
    }
}

__global__ __launch_bounds__(256) void gemm_kernel(const float* __restrict__ A,
                                                   const float* __restrict__ B,
                                                   float* __restrict__ C,
                                                   int M, int N, int K,
                                                   float alpha, int accumulate) {
    const int BM = 64, BN = 64, BK = 16;
    __shared__ float As[BK][BM];
    __shared__ float Bsh[BK][BN];
    int tid = threadIdx.x;
    int tx = tid % 16, ty = tid / 16;
    int row0 = blockIdx.y * BM, col0 = blockIdx.x * BN;
    float acc[4][4] = {};
    for (int k0 = 0; k0 < K; k0 += BK) {
        #pragma unroll
        for (int i = 0; i < 4; i++) {
            int e = tid * 4 + i;
            int m = e / BK, kk = e % BK;
            int gr = row0 + m, gk = k0 + kk;
            As[kk][m] = (gr < M && gk < K) ? A[(size_t)gr * K + gk] : 0.f;
        }
        #pragma unroll
        for (int i = 0; i < 4; i++) {
            int e = tid * 4 + i;
            int kk = e / BN, n = e % BN;
            int gk = k0 + kk, gc = col0 + n;
            Bsh[kk][n] = (gk < K && gc < N) ? B[(size_t)gk * N + gc] : 0.f;
        }
        __syncthreads();
        #pragma unroll
        for (int kk = 0; kk < BK; kk++) {
            float a[4], b[4];
            #pragma unroll
            for (int i = 0; i < 4; i++) a[i] = As[kk][ty * 4 + i];
            #pragma unroll
            for (int j = 0; j < 4; j++) b[j] = Bsh[kk][tx * 4 + j];
            #pragma unroll
            for (int i = 0; i < 4; i++)
                #pragma unroll
                for (int j = 0; j < 4; j++)
                    acc[i][j] += a[i] * b[j];
        }
        __syncthreads();
    }
    #pragma unroll
    for (int i = 0; i < 4; i++) {
        int r = row0 + ty * 4 + i;
        if (r >= M) continue;
        #pragma unroll
        for (int j = 0; j < 4; j++) {
            int c = col0 + tx * 4 + j;
            if (c >= N) continue;
            size_t idx = (size_t)r * N + c;
            float val = alpha * acc[i][j];
            if (accumulate) val += C[idx];
            C[idx] = val;
        }
    }
}

__global__ __launch_bounds__(256) void attn_kernel(const float* __restrict__ q,
                                                   const float* __restrict__ k,
                                                   const float* __restrict__ v,
                                                   float* __restrict__ ctx) {
    int qi = blockIdx.x;
    int hh = blockIdx.y;
    __shared__ float sc[T_LEN];
    __shared__ float qrow[DH_DIM];
    __shared__ float red[8];
    __shared__ float part[4][DH_DIM];
    int tid = threadIdx.x;
    int lane = tid & 63, wave = tid >> 6;
    const float* qp = q + (size_t)qi * D_DIM + hh * DH_DIM;
    if (tid < DH_DIM) qrow[tid] = qp[tid];
    __syncthreads();
    const float scale = 0.125f;
    for (int j = wave; j <= qi; j += 4) {
        const float* kp = k + (size_t)j * D_DIM + hh * DH_DIM;
        float p = qrow[lane] * kp[lane];
        for (int off = 32; off > 0; off >>= 1) p += __shfl_xor(p, off);
        if (lane == 0) sc[j] = p * scale;
    }
    __syncthreads();
    int n = qi + 1;
    float m = -1e30f;
    for (int j = tid; j < n; j += 256) m = fmaxf(m, sc[j]);
    for (int off = 32; off > 0; off >>= 1) m = fmaxf(m, __shfl_xor(m, off));
    if (lane == 0) red[wave] = m;
    __syncthreads();
    m = fmaxf(fmaxf(red[0], red[1]), fmaxf(red[2], red[3]));
    float s = 0.f;
    for (int j = tid; j < n; j += 256) { float e = expf(sc[j] - m); sc[j] = e; s += e; }
    for (int off = 32; off > 0; off >>= 1) s += __shfl_xor(s, off);
    if (lane == 0) red[4 + wave] = s;
    __syncthreads();
    s = red[4] + red[5] + red[6] + red[7];
    float inv = 1.0f / s;
    float acc = 0.f;
    for (int j = wave; j < n; j += 4) {
        acc += sc[j] * v[(size_t)j * D_DIM + hh * DH_DIM + lane];
    }
    part[wave][lane] = acc;
    __syncthreads();
    if (tid < DH_DIM) {
        float r = (part[0][tid] + part[1][tid] + part[2][tid] + part[3][tid]) * inv;
        ctx[(size_t)qi * D_DIM + hh * DH_DIM + tid] = r;
    }
}

__global__ void silu_mul_kernel(const float* __restrict__ g, const float* __restrict__ u,
                                float* __restrict__ out, int nelem) {
    int i = blockIdx.x * blockDim.x + threadIdx.x;
    if (i < nelem) {
        float gv = g[i];
        float sg = 1.0f / (1.0f + expf(-gv));
        out[i] = gv * sg * u[i];
    }
}

static inline void launch_gemm(const float* A, const float* B, float* C,
                               int M, int N, int K, float alpha, int accumulate,
                               hipStream_t stream) {
    dim3 grid((N + 63) / 64, (M + 63) / 64);
    gemm_kernel<<<grid, 256, 0, stream>>>(A, B, C, M, N, K, alpha, accumulate);
}

// =====================================================================================
extern "C" void kernel_launch(void* const* d_in, const int* in_sizes, int n_in,
                              void* d_out, int out_size, void* d_ws, size_t ws_size,
                              hipStream_t stream) {
    const int* packed = (const int*)d_in[0];
    const float* E  = (const float*)d_in[6];
    const float* Wsrc[7] = {(const float*)d_in[7],  (const float*)d_in[10], (const float*)d_in[13],
                            (const float*)d_in[16], (const float*)d_in[19], (const float*)d_in[22],
                            (const float*)d_in[25]};
    const float* Asrc[7] = {(const float*)d_in[8],  (const float*)d_in[11], (const float*)d_in[14],
                            (const float*)d_in[17], (const float*)d_in[20], (const float*)d_in[23],
                            (const float*)d_in[26]};
    const float* Bsrc[7] = {(const float*)d_in[9],  (const float*)d_in[12], (const float*)d_in[15],
                            (const float*)d_in[18], (const float*)d_in[21], (const float*)d_in[24],
                            (const float*)d_in[27]};
    const float* ln1 = (const float*)d_in[28];
    const float* ln2 = (const float*)d_in[29];
    const float* lnf = (const float*)d_in[30];

    const size_t DD = (size_t)D_DIM * D_DIM;     // 1M
    const size_t DF = (size_t)D_DIM * F_DIM;     // 4M
    const size_t wsizes[7] = {DD, DD, DD, DD, DF, DF, DF};
    const int Kdim[7] = {D_DIM, D_DIM, D_DIM, D_DIM, D_DIM, D_DIM, F_DIM};
    const int Ndim[7] = {D_DIM, D_DIM, D_DIM, D_DIM, F_DIM, F_DIM, D_DIM};

    // u16 buffer requirement (shared by big/mid paths)
    size_t u16_elems = 0;
    for (int p = 0; p < 7; p++) u16_elems += 2ull * N_LAYERS * wsizes[p];  // folded hi/lo
    u16_elems += 2ull * DD;            // h hi/lo
    u16_elems += 2ull * DD;            // ctx hi/lo
    u16_elems += 2ull * DF;            // ff hi/lo
    u16_elems += 6ull * DD;            // q,k,v hi/lo
    size_t f32_mid = (size_t)T_LEN * V_DIM + DD + 8 * DD;    // soft, x, 8-slot pool
    size_t f32_big = (size_t)T_LEN * V_DIM + DD + 16 * DD;   // soft, x, 16-slot pool
    size_t need_mid = u16_elems * 2 + f32_mid * 4 + 256;
    size_t need_big = u16_elems * 2 + f32_big * 4 + 256;

    if (ws_size >= need_mid) {
        const bool big = (ws_size >= need_big);
        ushort_t* ub = (ushort_t*)d_ws;
        size_t uo = 0;
        ushort_t *Whi[7], *Wlo[7];
        for (int p = 0; p < 7; p++) {
            Whi[p] = ub + uo; uo += (size_t)N_LAYERS * wsizes[p];
            Wlo[p] = ub + uo; uo += (size_t)N_LAYERS * wsizes[p];
        }
        ushort_t* h_hi = ub + uo; uo += DD;
        ushort_t* h_lo = ub + uo; uo += DD;
        ushort_t* c_hi = ub + uo; uo += DD;
        ushort_t* c_lo = ub + uo; uo += DD;
        ushort_t* f_hi = ub + uo; uo += DF;
        ushort_t* f_lo = ub + uo; uo += DF;
        ushort_t* qbh = ub + uo; uo += DD;
        ushort_t* qbl = ub + uo; uo += DD;
        ushort_t* kbh = ub + uo; uo += DD;
        ushort_t* kbl = ub + uo; uo += DD;
        ushort_t* vbh = ub + uo; uo += DD;
        ushort_t* vbl = ub + uo; uo += DD;
        float* fb = (float*)(ub + uo);
        size_t fo = 0;
        float* soft = fb + fo; fo += (size_t)T_LEN * V_DIM;
        float* x    = fb + fo; fo += DD;
        float* P    = fb + fo;   // partial pool: 8 DD slots (mid) or 16 DD = 4 DF slots (big)

        // fold weights (batched over layers)
        for (int p = 0; p < 7; p++) {
            dim3 grid(Ndim[p] / 64, Kdim[p] / 64, N_LAYERS);
            fold_kernel<<<grid, 256, 0, stream>>>(Wsrc[p], Asrc[p], Bsrc[p],
                                                  Whi[p], Wlo[p], Kdim[p], Ndim[p]);
        }

        init_soft_kernel<<<(T_LEN * V_DIM + 255) / 256, 256, 0, stream>>>(soft);

        const int n4 = (int)(DD / 4);
        const int qkvS = big ? 4 : 2;             // k-slices per QKV matrix
        const int dprS = big ? 16 : 8;            // k-slices for d-proj
        const int guS  = big ? 2 : 1;             // k-slices for G/U
        GemmJob jz = {};                           // unused slot filler

        for (int step = 0; step < N_STEPS; step++) {
            embed_rms_split_kernel<<<T_LEN, 256, 0, stream>>>(soft, E, ln1, x, h_hi, h_lo);
            for (int l = 0; l < N_LAYERS; l++) {
                {   // fused QKV, split-K x qkvS
                    GemmJob jq = {Whi[0] + l * DD, Wlo[0] + l * DD, P,                      nullptr, nullptr, 0, D_DIM};
                    GemmJob jk = {Whi[1] + l * DD, Wlo[1] + l * DD, P + (size_t)qkvS * DD,  nullptr, nullptr, 0, D_DIM};
                    GemmJob jv = {Whi[2] + l * DD, Wlo[2] + l * DD, P + (size_t)2 * qkvS * DD, nullptr, nullptr, 0, D_DIM};
                    gemm128_kernel<<<dim3(8, 8, 3 * qkvS), 256, 0, stream>>>(
                        h_hi, h_lo, D_DIM, D_DIM, qkvS, jq, jk, jv, jz, jz, jz, jz, jz);
                    qkv_sum_split_kernel<<<(int)(DD / 4 / 256), 256, 0, stream>>>(
                        P, qkvS, qbh, qbl, kbh, kbl, vbh, vbl);
                }
                attn_mfma_kernel<<<dim3(T_LEN / 64, H_NUM), 256, 0, stream>>>(
                    qbh, qbl, kbh, kbl, vbh, vbl, c_hi, c_lo);
                {   // o-proj split-K x8 + fused add + rms(ln2[l]) -> h
                    GemmJob jo = {Whi[3] + l * DD, Wlo[3] + l * DD, P, nullptr, nullptr, 0, D_DIM};
                    gemm128_kernel<<<dim3(8, 8, 8), 256, 0, stream>>>(
                        c_hi, c_lo, D_DIM, D_DIM, 8, jo, jz, jz, jz, jz, jz, jz, jz);
                    add_rms_split_kernel<<<T_LEN, 256, 0, stream>>>(
                        x, P, 8, ln2 + (size_t)l * D_DIM, h_hi, h_lo);
                }
                {   // G,U split-K x guS
                    GemmJob jg = {Whi[4] + l * DF, Wlo[4] + l * DF, P,                     nullptr, nullptr, 0, D_DIM};
                    GemmJob ju = {Whi[5] + l * DF, Wlo[5] + l * DF, P + (size_t)guS * DF,  nullptr, nullptr, 0, D_DIM};
                    gemm128_kernel<<<dim3(32, 8, 2 * guS), 256, 0, stream>>>(
                        h_hi, h_lo, D_DIM, F_DIM, guS, jg, ju, jz, jz, jz, jz, jz, jz);
                    silu_sum_split_kernel<<<(int)(DF / 4 / 256), 256, 0, stream>>>(
                        P, guS, f_hi, f_lo);
                }
                {   // d-proj split-K x dprS
                    GemmJob jd = {Whi[6] + l * DF, Wlo[6] + l * DF, P, nullptr, nullptr, 0, F_DIM};
                    gemm128_kernel<<<dim3(8, 8, dprS), 256, 0, stream>>>(
                        f_hi, f_lo, F_DIM, D_DIM, dprS, jd, jz, jz, jz, jz, jz, jz, jz);
                    if (l + 1 < N_LAYERS) {
                        add_rms_split_kernel<<<T_LEN, 256, 0, stream>>>(
                            x, P, dprS, ln1 + (size_t)(l + 1) * D_DIM, h_hi, h_lo);
                    } else {
                        addn_kernel<<<(n4 + 255) / 256, 256, 0, stream>>>(x, P, dprS, n4);
                    }
                }
            }
            head_kernel<<<T_LEN, 256, 0, stream>>>(x, lnf, E, packed, soft);
        }
        argmax_kernel<<<(T_LEN + 255) / 256, 256, 0, stream>>>(soft, (int*)d_out);
        return;
    }

    // -------- fallback: fp32 path --------
    float* ws = (float*)d_ws;
    size_t off = 0;
    float* soft = ws + off; off += (size_t)T_LEN * V_DIM;
    float* x    = ws + off; off += (size_t)T_LEN * D_DIM;
    float* h    = ws + off; off += (size_t)T_LEN * D_DIM;
    float* qb   = ws + off; off += (size_t)T_LEN * D_DIM;
    float* kb   = ws + off; off += (size_t)T_LEN * D_DIM;
    float* vb   = ws + off; off += (size_t)T_LEN * D_DIM;
    float* cb   = ws + off; off += (size_t)T_LEN * D_DIM;
    float* gb   = ws + off; off += (size_t)T_LEN * F_DIM;
    float* ubf  = ws + off; off += (size_t)T_LEN * F_DIM;
    float* tmp  = ws + off; off += (size_t)T_LEN * R_LORA;

    init_soft_kernel<<<(T_LEN * V_DIM + 255) / 256, 256, 0, stream>>>(soft);
    for (int step = 0; step < N_STEPS; step++) {
        embed_kernel<<<T_LEN, 256, 0, stream>>>(soft, E, x);
        for (int l = 0; l < N_LAYERS; l++) {
            const float* ln1_l = ln1 + (size_t)l * D_DIM;
            const float* ln2_l = ln2 + (size_t)l * D_DIM;
            rms_kernel<<<T_LEN, 256, 0, stream>>>(x, ln1_l, h);
            launch_gemm(h, Asrc[0] + (size_t)l * D_DIM * R_LORA, tmp, T_LEN, R_LORA, D_DIM, 1.0f, 0, stream);
            launch_gemm(h, Wsrc[0] + (size_t)l * DD, qb, T_LEN, D_DIM, D_DIM, 1.0f, 0, stream);
            launch_gemm(tmp, Bsrc[0] + (size_t)l * R_LORA * D_DIM, qb, T_LEN, D_DIM, R_LORA, LORA_SCALE, 1, stream);
            launch_gemm(h, Asrc[1] + (size_t)l * D_DIM * R_LORA, tmp, T_LEN, R_LORA, D_DIM, 1.0f, 0, stream);
            launch_gemm(h, Wsrc[1] + (size_t)l * DD, kb, T_LEN, D_DIM, D_DIM, 1.0f, 0, stream);
            launch_gemm(tmp, Bsrc[1] + (size_t)l * R_LORA * D_DIM, kb, T_LEN, D_DIM, R_LORA, LORA_SCALE, 1, stream);
            launch_gemm(h, Asrc[2] + (size_t)l * D_DIM * R_LORA, tmp, T_LEN, R_LORA, D_DIM, 1.0f, 0, stream);
            launch_gemm(h, Wsrc[2] + (size_t)l * DD, vb, T_LEN, D_DIM, D_DIM, 1.0f, 0, stream);
            launch_gemm(tmp, Bsrc[2] + (size_t)l * R_LORA * D_DIM, vb, T_LEN, D_DIM, R_LORA, LORA_SCALE, 1, stream);
            attn_kernel<<<dim3(T_LEN, H_NUM), 256, 0, stream>>>(qb, kb, vb, cb);
            launch_gemm(cb, Asrc[3] + (size_t)l * D_DIM * R_LORA, tmp, T_LEN, R_LORA, D_DIM, 1.0f, 0, stream);
            launch_gemm(cb, Wsrc[3] + (size_t)l * DD, x, T_LEN, D_DIM, D_DIM, 1.0f, 1, stream);
            launch_gemm(tmp, Bsrc[3] + (size_t)l * R_LORA * D_DIM, x, T_LEN, D_DIM, R_LORA, LORA_SCALE, 1, stream);
            rms_kernel<<<T_LEN, 256, 0, stream>>>(x, ln2_l, h);
            launch_gemm(h, Asrc[4] + (size_t)l * D_DIM * R_LORA, tmp, T_LEN, R_LORA, D_DIM, 1.0f, 0, stream);
            launch_gemm(h, Wsrc[4] + (size_t)l * DF, gb, T_LEN, F_DIM, D_DIM, 1.0f, 0, stream);
            launch_gemm(tmp, Bsrc[4] + (size_t)l * R_LORA * F_DIM, gb, T_LEN, F_DIM, R_LORA, LORA_SCALE, 1, stream);
            launch_gemm(h, Asrc[5] + (size_t)l * D_DIM * R_LORA, tmp, T_LEN, R_LORA, D_DIM, 1.0f, 0, stream);
            launch_gemm(h, Wsrc[5] + (size_t)l * DF, ubf, T_LEN, F_DIM, D_DIM, 1.0f, 0, stream);
            launch_gemm(tmp, Bsrc[5] + (size_t)l * R_LORA * F_DIM, ubf, T_LEN, F_DIM, R_LORA, LORA_SCALE, 1, stream);
            silu_mul_kernel<<<(T_LEN * F_DIM + 255) / 256, 256, 0, stream>>>(gb, ubf, gb, T_LEN * F_DIM);
            launch_gemm(gb, Asrc[6] + (size_t)l * F_DIM * R_LORA, tmp, T_LEN, R_LORA, F_DIM, 1.0f, 0, stream);
            launch_gemm(gb, Wsrc[6] + (size_t)l * DF, x, T_LEN, D_DIM, F_DIM, 1.0f, 1, stream);
            launch_gemm(tmp, Bsrc[6] + (size_t)l * R_LORA * D_DIM, x, T_LEN, D_DIM, R_LORA, LORA_SCALE, 1, stream);
        }
        head_kernel<<<T_LEN, 256, 0, stream>>>(x, lnf, E, packed, soft);
    }
    argmax_kernel<<<(T_LEN + 255) / 256, 256, 0, stream>>>(soft, (int*)d_out);
}

// Round 8
// 1033.973 us; speedup vs baseline: 1.1617x; 1.1617x over previous
//
#include <hip/hip_runtime.h>
#include <hip/hip_bf16.h>

#define T_LEN 1024
#define D_DIM 1024
#define V_DIM 17
#define H_NUM 16
#define DH_DIM 64
#define F_DIM 4096
#define R_LORA 32
#define N_LAYERS 2
#define N_STEPS 2
#define MASK_ID 16
#define LORA_SCALE 2.0f

typedef __attribute__((ext_vector_type(8))) short bfx8;   // 8 bf16 in 4 VGPRs
typedef __attribute__((ext_vector_type(4))) float f32x4;

typedef unsigned short ushort_t;
typedef unsigned int uint_t;

#define AS1 __attribute__((address_space(1)))
#define AS3 __attribute__((address_space(3)))

__device__ __forceinline__ void gload16(const ushort_t* g, ushort_t* l) {
    __builtin_amdgcn_global_load_lds((const AS1 void*)(const void*)g,
                                     (AS3 void*)(void*)l, 16, 0, 0);
}

__device__ __forceinline__ ushort_t f2bf(float v) {
    __hip_bfloat16 h = __float2bfloat16(v);
    return __builtin_bit_cast(unsigned short, h);
}
__device__ __forceinline__ float bf2f(ushort_t u) {
    return __uint_as_float(((uint_t)u) << 16);
}
__device__ __forceinline__ void split4_store(float y0, float y1, float y2, float y3,
                                             ushort_t* __restrict__ hi, ushort_t* __restrict__ lo,
                                             size_t idx) {
    ushort_t h0 = f2bf(y0), h1 = f2bf(y1), h2 = f2bf(y2), h3 = f2bf(y3);
    ushort_t l0 = f2bf(y0 - bf2f(h0));
    ushort_t l1 = f2bf(y1 - bf2f(h1));
    ushort_t l2 = f2bf(y2 - bf2f(h2));
    ushort_t l3 = f2bf(y3 - bf2f(h3));
    uint2 hv, lv;
    hv.x = (uint_t)h0 | ((uint_t)h1 << 16);
    hv.y = (uint_t)h2 | ((uint_t)h3 << 16);
    lv.x = (uint_t)l0 | ((uint_t)l1 << 16);
    lv.y = (uint_t)l2 | ((uint_t)l3 << 16);
    *(uint2*)(hi + idx) = hv;
    *(uint2*)(lo + idx) = lv;
}

// ---------------- init soft ----------------
__global__ void init_soft_kernel(float* __restrict__ soft) {
    int idx = blockIdx.x * blockDim.x + threadIdx.x;
    if (idx < T_LEN * V_DIM) {
        soft[idx] = ((idx % V_DIM) == MASK_ID) ? 1.0f : 0.0f;
    }
}

// ---------------- fused embed + rms + split ----------------
__global__ __launch_bounds__(256) void embed_rms_split_kernel(
    const float* __restrict__ soft, const float* __restrict__ E,
    const float* __restrict__ w, float* __restrict__ x,
    ushort_t* __restrict__ hi, ushort_t* __restrict__ lo)
{
    const int t = blockIdx.x, tid = threadIdx.x;
    __shared__ float srow[V_DIM];
    __shared__ float red[4];
    if (tid < V_DIM) srow[tid] = soft[t * V_DIM + tid];
    __syncthreads();
    const int d0 = tid * 4;
    float4 acc = {0.f, 0.f, 0.f, 0.f};
    #pragma unroll
    for (int v = 0; v < V_DIM; v++) {
        float s = srow[v];
        float4 e = *(const float4*)(E + (size_t)v * D_DIM + d0);
        acc.x = fmaf(s, e.x, acc.x);
        acc.y = fmaf(s, e.y, acc.y);
        acc.z = fmaf(s, e.z, acc.z);
        acc.w = fmaf(s, e.w, acc.w);
    }
    size_t base = (size_t)t * D_DIM + d0;
    *(float4*)(x + base) = acc;
    float ss = acc.x * acc.x + acc.y * acc.y + acc.z * acc.z + acc.w * acc.w;
    const int lane = tid & 63, wv = tid >> 6;
    #pragma unroll
    for (int off = 32; off > 0; off >>= 1) ss += __shfl_xor(ss, off);
    if (lane == 0) red[wv] = ss;
    __syncthreads();
    ss = red[0] + red[1] + red[2] + red[3];
    const float r = 1.0f / sqrtf(ss * (1.0f / D_DIM) + 1e-6f);
    const float4 wv4 = *(const float4*)(w + d0);
    split4_store(acc.x * r * wv4.x, acc.y * r * wv4.y, acc.z * r * wv4.z, acc.w * r * wv4.w,
                 hi, lo, base);
}

// ---------------- fold v3: out^T = split(W + 2*A@B) ----------------
__global__ __launch_bounds__(256) void fold_kernel(
    const float* __restrict__ W,   // [L,K,N]
    const float* __restrict__ A,   // [L,K,R]
    const float* __restrict__ Bm,  // [L,R,N]
    ushort_t* __restrict__ oHi,    // [L,N,K]
    ushort_t* __restrict__ oLo,
    int K, int N)
{
    const int l = blockIdx.z;
    W   += (size_t)l * K * N;
    A   += (size_t)l * K * R_LORA;
    Bm  += (size_t)l * R_LORA * N;
    oHi += (size_t)l * K * N;
    oLo += (size_t)l * K * N;
    __shared__ float Als[64][R_LORA + 1];
    __shared__ uint_t tile[64][65];
    const int tid = threadIdx.x;
    const int n0 = blockIdx.x * 64, k0 = blockIdx.y * 64;

    {
        const int row = tid >> 2, c0 = (tid & 3) * 8;
        const float* src = A + (size_t)(k0 + row) * R_LORA + c0;
        float4 a0 = *(const float4*)(src);
        float4 a1 = *(const float4*)(src + 4);
        Als[row][c0 + 0] = a0.x; Als[row][c0 + 1] = a0.y;
        Als[row][c0 + 2] = a0.z; Als[row][c0 + 3] = a0.w;
        Als[row][c0 + 4] = a1.x; Als[row][c0 + 5] = a1.y;
        Als[row][c0 + 6] = a1.z; Als[row][c0 + 7] = a1.w;
    }
    const int nl = tid & 63, kq = tid >> 6;
    float wreg[16];
    #pragma unroll
    for (int i = 0; i < 16; i++)
        wreg[i] = W[(size_t)(k0 + kq * 16 + i) * N + n0 + nl];
    float breg[R_LORA];
    #pragma unroll
    for (int r = 0; r < R_LORA; r++) breg[r] = Bm[(size_t)r * N + n0 + nl];
    __syncthreads();
    #pragma unroll
    for (int i = 0; i < 16; i++) {
        const int kl = kq * 16 + i;
        float acc = 0.f;
        #pragma unroll
        for (int r = 0; r < R_LORA; r++) acc = fmaf(Als[kl][r], breg[r], acc);
        float val = wreg[i] + LORA_SCALE * acc;
        ushort_t h = f2bf(val);
        tile[kl][nl] = ((uint_t)h << 16) | (uint_t)f2bf(val - bf2f(h));
    }
    __syncthreads();
    {
        const int nl2 = tid >> 2;
        const int kc0 = (tid & 3) * 16;
        ushort_t hb[16], lb[16];
        #pragma unroll
        for (int i = 0; i < 16; i++) {
            uint_t pk = tile[kc0 + i][nl2];
            hb[i] = (ushort_t)(pk >> 16);
            lb[i] = (ushort_t)(pk & 0xffffu);
        }
        size_t idx = (size_t)(n0 + nl2) * K + k0 + kc0;
        *(uint4*)(oHi + idx)     = *(uint4*)&hb[0];
        *(uint4*)(oHi + idx + 8) = *(uint4*)&hb[8];
        *(uint4*)(oLo + idx)     = *(uint4*)&lb[0];
        *(uint4*)(oLo + idx + 8) = *(uint4*)&lb[8];
    }
}

// ---------------- 128x128 MFMA split-bf16 GEMM, 2-phase double-buffered ----------------
// Prefetch tile t+1 into buf^1 via global_load_lds BEFORE computing buf (T3 min-2-phase);
// __syncthreads' implicit vmcnt(0)+lgkmcnt(0) drain makes the swap race-free.
struct GemmJob {
    const ushort_t* Bh;
    const ushort_t* Bl;
    float* Cf;        // if non-null: f32 store (partials: slot s at Cf + s*T_LEN*N)
    ushort_t* Ch;     // else split store (kslices must be 1)
    ushort_t* Cl;
    int k0, k1;
};

__global__ __launch_bounds__(256) void gemm128_kernel(
    const ushort_t* __restrict__ Ahi, const ushort_t* __restrict__ Alo,
    int K, int N, int kslices,
    GemmJob j0, GemmJob j1, GemmJob j2, GemmJob j3,
    GemmJob j4, GemmJob j5, GemmJob j6, GemmJob j7)
{
    GemmJob jb;
    int s;
    {
        const int z = blockIdx.z;
        const int ji = z / kslices;
        s = z - ji * kslices;
        if      (ji == 0) jb = j0; else if (ji == 1) jb = j1;
        else if (ji == 2) jb = j2; else if (ji == 3) jb = j3;
        else if (ji == 4) jb = j4; else if (ji == 5) jb = j5;
        else if (ji == 6) jb = j6; else jb = j7;
    }
    const int klen = (jb.k1 - jb.k0) / kslices;
    const int myk0 = jb.k0 + s * klen;
    const int myk1 = myk0 + klen;
    float* Cf = jb.Cf ? jb.Cf + (size_t)s * T_LEN * (size_t)N : nullptr;

    __shared__ ushort_t Ash[2][128][32];
    __shared__ ushort_t Asl[2][128][32];
    __shared__ ushort_t Bsh[2][128][32];
    __shared__ ushort_t Bsl[2][128][32];

    const int tid = threadIdx.x, lane = tid & 63, w = tid >> 6;
    const int l15 = lane & 15, lg = lane >> 4;
    const int m0 = blockIdx.y * 128, n0 = blockIdx.x * 128;
    const int wm = (w >> 1) * 64, wn = (w & 1) * 64;

    const int r0 = w * 32;
    const int rsub = lane >> 2;
    const int cs = lane & 3;
    const int csl = (cs ^ ((rsub >> 1) & 3)) * 8;   // pre-swizzled source col (shorts)
    const int rsl = (lg ^ ((l15 >> 1) & 3)) * 8;    // swizzled read col (shorts)

    f32x4 acc[4][4];
    #pragma unroll
    for (int i = 0; i < 4; i++)
        #pragma unroll
        for (int j = 0; j < 4; j++) acc[i][j] = f32x4{0.f, 0.f, 0.f, 0.f};

    const size_t rowA = (size_t)(m0 + r0 + rsub) * K;
    const size_t rowB = (size_t)(n0 + r0 + rsub) * K;
    const size_t rstep = (size_t)16 * K;

    auto stage = [&](int b, int kk) {
        const ushort_t* a0 = Ahi + rowA + kk + csl;
        const ushort_t* a1 = Alo + rowA + kk + csl;
        const ushort_t* b0 = jb.Bh + rowB + kk + csl;
        const ushort_t* b1 = jb.Bl + rowB + kk + csl;
        gload16(a0,         &Ash[b][r0][0]);
        gload16(a0 + rstep, &Ash[b][r0 + 16][0]);
        gload16(a1,         &Asl[b][r0][0]);
        gload16(a1 + rstep, &Asl[b][r0 + 16][0]);
        gload16(b0,         &Bsh[b][r0][0]);
        gload16(b0 + rstep, &Bsh[b][r0 + 16][0]);
        gload16(b1,         &Bsl[b][r0][0]);
        gload16(b1 + rstep, &Bsl[b][r0 + 16][0]);
    };

    stage(0, myk0);
    __syncthreads();              // drain prologue loads
    int cur = 0;
    for (int kk = myk0; kk < myk1; kk += 32) {
        if (kk + 32 < myk1) stage(cur ^ 1, kk + 32);   // prefetch next (in flight during MFMA)
        bfx8 bh[4], bl[4];
        #pragma unroll
        for (int ni = 0; ni < 4; ni++) {
            bh[ni] = *(const bfx8*)&Bsh[cur][wn + ni * 16 + l15][rsl];
            bl[ni] = *(const bfx8*)&Bsl[cur][wn + ni * 16 + l15][rsl];
        }
        #pragma unroll
        for (int mi = 0; mi < 4; mi++) {
            bfx8 ah = *(const bfx8*)&Ash[cur][wm + mi * 16 + l15][rsl];
            bfx8 al = *(const bfx8*)&Asl[cur][wm + mi * 16 + l15][rsl];
            #pragma unroll
            for (int ni = 0; ni < 4; ni++) {
                acc[mi][ni] = __builtin_amdgcn_mfma_f32_16x16x32_bf16(ah, bh[ni], acc[mi][ni], 0, 0, 0);
                acc[mi][ni] = __builtin_amdgcn_mfma_f32_16x16x32_bf16(ah, bl[ni], acc[mi][ni], 0, 0, 0);
                acc[mi][ni] = __builtin_amdgcn_mfma_f32_16x16x32_bf16(al, bh[ni], acc[mi][ni], 0, 0, 0);
            }
        }
        __syncthreads();          // drains prefetch vmcnt + guards buffer reuse
        cur ^= 1;
    }

    if (Cf) {
        #pragma unroll
        for (int mi = 0; mi < 4; mi++)
            #pragma unroll
            for (int ni = 0; ni < 4; ni++) {
                int col = n0 + wn + ni * 16 + l15;
                #pragma unroll
                for (int i = 0; i < 4; i++) {
                    int row = m0 + wm + mi * 16 + lg * 4 + i;
                    Cf[(size_t)row * N + col] = acc[mi][ni][i];
                }
            }
    } else {
        #pragma unroll
        for (int mi = 0; mi < 4; mi++)
            #pragma unroll
            for (int ni = 0; ni < 4; ni++) {
                int col = n0 + wn + ni * 16 + l15;
                #pragma unroll
                for (int i = 0; i < 4; i++) {
                    int row = m0 + wm + mi * 16 + lg * 4 + i;
                    size_t idx = (size_t)row * N + col;
                    float v = acc[mi][ni][i];
                    ushort_t h = f2bf(v);
                    jb.Ch[idx] = h;
                    jb.Cl[idx] = f2bf(v - bf2f(h));
                }
            }
    }
}

// ---------------- qkv epilogue: q/k/v = split(sum of S partials each) ----------------
__global__ __launch_bounds__(256) void qkv_sum_split_kernel(
    const float* __restrict__ P, int S,
    ushort_t* __restrict__ qbh, ushort_t* __restrict__ qbl,
    ushort_t* __restrict__ kbh, ushort_t* __restrict__ kbl,
    ushort_t* __restrict__ vbh, ushort_t* __restrict__ vbl)
{
    const size_t DD1 = (size_t)T_LEN * D_DIM;
    size_t e = ((size_t)blockIdx.x * 256 + threadIdx.x) * 4;
    float4 q = {0,0,0,0}, k = {0,0,0,0}, v = {0,0,0,0};
    for (int j = 0; j < S; j++) {
        float4 a = *(const float4*)(P + (size_t)j * DD1 + e);
        q.x += a.x; q.y += a.y; q.z += a.z; q.w += a.w;
        float4 b = *(const float4*)(P + (size_t)(S + j) * DD1 + e);
        k.x += b.x; k.y += b.y; k.z += b.z; k.w += b.w;
        float4 c = *(const float4*)(P + (size_t)(2 * S + j) * DD1 + e);
        v.x += c.x; v.y += c.y; v.z += c.z; v.w += c.w;
    }
    split4_store(q.x, q.y, q.z, q.w, qbh, qbl, e);
    split4_store(k.x, k.y, k.z, k.w, kbh, kbl, e);
    split4_store(v.x, v.y, v.z, v.w, vbh, vbl, e);
}

// ---------------- x += sum of nparts DD-sized partials ----------------
__global__ void addn_kernel(float* __restrict__ x, const float* __restrict__ P,
                            int nparts, int n4) {
    int i = blockIdx.x * blockDim.x + threadIdx.x;
    if (i < n4) {
        const size_t DD1 = (size_t)T_LEN * D_DIM;
        size_t e = (size_t)i * 4;
        float4 xv = *(const float4*)(x + e);
        for (int j = 0; j < nparts; j++) {
            float4 p = *(const float4*)(P + (size_t)j * DD1 + e);
            xv.x += p.x; xv.y += p.y; xv.z += p.z; xv.w += p.w;
        }
        *(float4*)(x + e) = xv;
    }
}

// ---------------- fused: x += sum(nparts); h = split(rms(x,w)) ----------------
__global__ __launch_bounds__(256) void add_rms_split_kernel(
    float* __restrict__ x, const float* __restrict__ P, int nparts,
    const float* __restrict__ w, ushort_t* __restrict__ hi, ushort_t* __restrict__ lo)
{
    const int t = blockIdx.x, tid = threadIdx.x;
    const size_t DD1 = (size_t)T_LEN * D_DIM;
    size_t base = (size_t)t * D_DIM + tid * 4;
    float4 xv = *(const float4*)(x + base);
    for (int j = 0; j < nparts; j++) {
        float4 p = *(const float4*)(P + (size_t)j * DD1 + base);
        xv.x += p.x; xv.y += p.y; xv.z += p.z; xv.w += p.w;
    }
    *(float4*)(x + base) = xv;
    float ss = xv.x * xv.x + xv.y * xv.y + xv.z * xv.z + xv.w * xv.w;
    __shared__ float red[4];
    const int lane = tid & 63, wv = tid >> 6;
    #pragma unroll
    for (int off = 32; off > 0; off >>= 1) ss += __shfl_xor(ss, off);
    if (lane == 0) red[wv] = ss;
    __syncthreads();
    ss = red[0] + red[1] + red[2] + red[3];
    const float r = 1.0f / sqrtf(ss * (1.0f / D_DIM) + 1e-6f);
    const float4 wv4 = *(const float4*)(w + tid * 4);
    split4_store(xv.x * r * wv4.x, xv.y * r * wv4.y, xv.z * r * wv4.z, xv.w * r * wv4.w,
                 hi, lo, base);
}

// ---------------- silu epilogue ----------------
__global__ void silu_sum_split_kernel(const float* __restrict__ P, int parts,
                                      ushort_t* __restrict__ hi, ushort_t* __restrict__ lo) {
    const size_t DF1 = (size_t)T_LEN * F_DIM;
    size_t e = ((size_t)blockIdx.x * 256 + threadIdx.x) * 4;
    float4 g = {0,0,0,0}, u = {0,0,0,0};
    for (int j = 0; j < parts; j++) {
        float4 a = *(const float4*)(P + (size_t)j * DF1 + e);
        g.x += a.x; g.y += a.y; g.z += a.z; g.w += a.w;
        float4 b = *(const float4*)(P + (size_t)(parts + j) * DF1 + e);
        u.x += b.x; u.y += b.y; u.z += b.z; u.w += b.w;
    }
    float y0 = g.x / (1.f + expf(-g.x)) * u.x;
    float y1 = g.y / (1.f + expf(-g.y)) * u.y;
    float y2 = g.z / (1.f + expf(-g.z)) * u.z;
    float y3 = g.w / (1.f + expf(-g.w)) * u.w;
    split4_store(y0, y1, y2, y3, hi, lo, e);
}

// ---------------- MFMA flash attention, T14 async-STAGE (prefetch next K/V tile to regs) ----------------
#define KS_PAD 72
#define P_PAD 72
__global__ __launch_bounds__(256, 1) void attn_mfma_kernel(
    const ushort_t* __restrict__ qh, const ushort_t* __restrict__ ql,
    const ushort_t* __restrict__ kh, const ushort_t* __restrict__ kl,
    const ushort_t* __restrict__ vh, const ushort_t* __restrict__ vl,
    ushort_t* __restrict__ chi, ushort_t* __restrict__ clo)
{
    __shared__ ushort_t Ksh[64][KS_PAD];
    __shared__ ushort_t Ksl[64][KS_PAD];
    __shared__ ushort_t VTh[64][KS_PAD];
    __shared__ ushort_t VTl[64][KS_PAD];
    __shared__ ushort_t Ph[4][16][P_PAD];
    __shared__ ushort_t Pl[4][16][P_PAD];

    const int qt = blockIdx.x, hh = blockIdx.y;
    const int tid = threadIdx.x, w = tid >> 6, lane = tid & 63;
    const int l15 = lane & 15, lg = lane >> 4;
    const int q0 = qt * 64;
    const int hcol = hh * DH_DIM;

    bfx8 qa_h[2], qa_l[2];
    {
        size_t qrow = (size_t)(q0 + w * 16 + l15) * D_DIM + hcol;
        #pragma unroll
        for (int ks = 0; ks < 2; ks++) {
            qa_h[ks] = *(const bfx8*)(qh + qrow + ks * 32 + lg * 8);
            qa_l[ks] = *(const bfx8*)(ql + qrow + ks * 32 + lg * 8);
        }
    }

    f32x4 o[4];
    #pragma unroll
    for (int ni = 0; ni < 4; ni++) o[ni] = f32x4{0.f, 0.f, 0.f, 0.f};
    float mrun[4], lrun[4];
    #pragma unroll
    for (int i = 0; i < 4; i++) { mrun[i] = -3.0e38f; lrun[i] = 0.f; }

    const int srow = tid >> 2;
    const int sseg = (tid & 3) * 16;
    const int vp = tid & 31;
    const int vd0 = (tid >> 5) * 8;

    // register-staged tile (T14: issue-early / write-late)
    uint4 kh0, kh1, kl0, kl1, vh0, vh1, vl0, vl1;
    auto load_tile = [&](int kt) {
        size_t src = (size_t)(kt * 64 + srow) * D_DIM + hcol + sseg;
        kh0 = *(const uint4*)(kh + src);
        kh1 = *(const uint4*)(kh + src + 8);
        kl0 = *(const uint4*)(kl + src);
        kl1 = *(const uint4*)(kl + src + 8);
        size_t s0 = (size_t)(kt * 64 + 2 * vp) * D_DIM + hcol + vd0;
        vh0 = *(const uint4*)(vh + s0);
        vh1 = *(const uint4*)(vh + s0 + D_DIM);
        vl0 = *(const uint4*)(vl + s0);
        vl1 = *(const uint4*)(vl + s0 + D_DIM);
    };
    load_tile(0);

    for (int kt = 0; kt <= qt; kt++) {
        __syncthreads();    // previous compute done: LDS writable
        {   // write staged regs -> LDS
            *(uint4*)&Ksh[srow][sseg]     = kh0;
            *(uint4*)&Ksh[srow][sseg + 8] = kh1;
            *(uint4*)&Ksl[srow][sseg]     = kl0;
            *(uint4*)&Ksl[srow][sseg + 8] = kl1;
            const ushort_t* a = (const ushort_t*)&vh0;
            const ushort_t* b = (const ushort_t*)&vh1;
            const ushort_t* c = (const ushort_t*)&vl0;
            const ushort_t* d = (const ushort_t*)&vl1;
            #pragma unroll
            for (int j = 0; j < 8; j++) {
                *(uint_t*)&VTh[vd0 + j][2 * vp] = (uint_t)a[j] | ((uint_t)b[j] << 16);
                *(uint_t*)&VTl[vd0 + j][2 * vp] = (uint_t)c[j] | ((uint_t)d[j] << 16);
            }
        }
        __syncthreads();    // tile visible
        if (kt < qt) load_tile(kt + 1);   // prefetch next; latency hidden under compute

        f32x4 s[4];
        #pragma unroll
        for (int ni = 0; ni < 4; ni++) s[ni] = f32x4{0.f, 0.f, 0.f, 0.f};
        #pragma unroll
        for (int ks = 0; ks < 2; ks++) {
            #pragma unroll
            for (int ni = 0; ni < 4; ni++) {
                bfx8 bh = *(const bfx8*)&Ksh[ni * 16 + l15][ks * 32 + lg * 8];
                bfx8 bl = *(const bfx8*)&Ksl[ni * 16 + l15][ks * 32 + lg * 8];
                s[ni] = __builtin_amdgcn_mfma_f32_16x16x32_bf16(qa_h[ks], bh, s[ni], 0, 0, 0);
                s[ni] = __builtin_amdgcn_mfma_f32_16x16x32_bf16(qa_h[ks], bl, s[ni], 0, 0, 0);
                s[ni] = __builtin_amdgcn_mfma_f32_16x16x32_bf16(qa_l[ks], bh, s[ni], 0, 0, 0);
            }
        }

        const int kbase = kt * 64;
        float rmax[4];
        #pragma unroll
        for (int i = 0; i < 4; i++) rmax[i] = -3.0e38f;
        #pragma unroll
        for (int ni = 0; ni < 4; ni++) {
            int kc = kbase + ni * 16 + l15;
            #pragma unroll
            for (int i = 0; i < 4; i++) {
                int qrow = q0 + w * 16 + lg * 4 + i;
                float v = s[ni][i] * 0.125f;
                v = (kc <= qrow) ? v : -3.0e38f;
                s[ni][i] = v;
                rmax[i] = fmaxf(rmax[i], v);
            }
        }
        #pragma unroll
        for (int off = 1; off < 16; off <<= 1) {
            #pragma unroll
            for (int i = 0; i < 4; i++) rmax[i] = fmaxf(rmax[i], __shfl_xor(rmax[i], off));
        }
        float psum[4];
        #pragma unroll
        for (int i = 0; i < 4; i++) {
            float nm = fmaxf(mrun[i], rmax[i]);
            float sc = __expf(mrun[i] - nm);
            lrun[i] *= sc;
            #pragma unroll
            for (int ni = 0; ni < 4; ni++) o[ni][i] *= sc;
            mrun[i] = nm;
            psum[i] = 0.f;
        }
        #pragma unroll
        for (int ni = 0; ni < 4; ni++) {
            #pragma unroll
            for (int i = 0; i < 4; i++) {
                float e = __expf(s[ni][i] - mrun[i]);
                s[ni][i] = e;
                psum[i] += e;
            }
        }
        #pragma unroll
        for (int off = 1; off < 16; off <<= 1) {
            #pragma unroll
            for (int i = 0; i < 4; i++) psum[i] += __shfl_xor(psum[i], off);
        }
        #pragma unroll
        for (int i = 0; i < 4; i++) lrun[i] += psum[i];

        #pragma unroll
        for (int ni = 0; ni < 4; ni++) {
            #pragma unroll
            for (int i = 0; i < 4; i++) {
                float e = s[ni][i];
                ushort_t hp = f2bf(e);
                Ph[w][lg * 4 + i][ni * 16 + l15] = hp;
                Pl[w][lg * 4 + i][ni * 16 + l15] = f2bf(e - bf2f(hp));
            }
        }
        #pragma unroll
        for (int ks = 0; ks < 2; ks++) {
            bfx8 ah = *(const bfx8*)&Ph[w][l15][ks * 32 + lg * 8];
            bfx8 al = *(const bfx8*)&Pl[w][l15][ks * 32 + lg * 8];
            #pragma unroll
            for (int ni = 0; ni < 4; ni++) {
                bfx8 bh = *(const bfx8*)&VTh[ni * 16 + l15][ks * 32 + lg * 8];
                bfx8 bl = *(const bfx8*)&VTl[ni * 16 + l15][ks * 32 + lg * 8];
                o[ni] = __builtin_amdgcn_mfma_f32_16x16x32_bf16(ah, bh, o[ni], 0, 0, 0);
                o[ni] = __builtin_amdgcn_mfma_f32_16x16x32_bf16(ah, bl, o[ni], 0, 0, 0);
                o[ni] = __builtin_amdgcn_mfma_f32_16x16x32_bf16(al, bh, o[ni], 0, 0, 0);
            }
        }
    }

    #pragma unroll
    for (int i = 0; i < 4; i++) {
        float inv = 1.0f / lrun[i];
        #pragma unroll
        for (int ni = 0; ni < 4; ni++) o[ni][i] *= inv;
    }
    #pragma unroll
    for (int ni = 0; ni < 4; ni++) {
        int col = hcol + ni * 16 + l15;
        #pragma unroll
        for (int i = 0; i < 4; i++) {
            int row = q0 + w * 16 + lg * 4 + i;
            size_t idx = (size_t)row * D_DIM + col;
            float v = o[ni][i];
            ushort_t hp = f2bf(v);
            chi[idx] = hp;
            clo[idx] = f2bf(v - bf2f(hp));
        }
    }
}

// ---------------- head ----------------
__global__ __launch_bounds__(256) void head_kernel(const float* __restrict__ x,
                                                   const float* __restrict__ lnf,
                                                   const float* __restrict__ E,
                                                   const int* __restrict__ tok,
                                                   float* __restrict__ soft) {
    int t = blockIdx.x;
    int tid = threadIdx.x;
    __shared__ float y[D_DIM];
    __shared__ float red[4];
    __shared__ float logits[V_DIM];
    const float* xr = x + (size_t)t * D_DIM;
    float ss = 0.f;
    for (int d = tid; d < D_DIM; d += 256) { float v = xr[d]; ss += v * v; }
    int lane = tid & 63, wave = tid >> 6;
    for (int off = 32; off > 0; off >>= 1) ss += __shfl_xor(ss, off);
    if (lane == 0) red[wave] = ss;
    __syncthreads();
    ss = red[0] + red[1] + red[2] + red[3];
    float r = 1.0f / sqrtf(ss * (1.0f / D_DIM) + 1e-6f);
    for (int d = tid; d < D_DIM; d += 256) y[d] = xr[d] * r * lnf[d];
    __syncthreads();
    for (int vv = wave; vv < V_DIM; vv += 4) {
        float p = 0.f;
        for (int d = lane; d < D_DIM; d += 64) p += y[d] * E[vv * D_DIM + d];
        for (int off = 32; off > 0; off >>= 1) p += __shfl_xor(p, off);
        if (lane == 0) logits[vv] = p;
    }
    __syncthreads();
    if (tid == 0) {
        int tk = tok[t];
        if (tk != MASK_ID) {
            for (int vv = 0; vv < V_DIM; vv++) soft[t * V_DIM + vv] = (vv == tk) ? 1.f : 0.f;
        } else {
            float mx = -1e30f;
            for (int vv = 0; vv < V_DIM; vv++) mx = fmaxf(mx, logits[vv]);
            float sm = 0.f;
            float e[V_DIM];
            for (int vv = 0; vv < V_DIM; vv++) { e[vv] = expf(logits[vv] - mx); sm += e[vv]; }
            float invs = 1.0f / sm;
            for (int vv = 0; vv < V_DIM; vv++) soft[t * V_DIM + vv] = e[vv] * invs;
        }
    }
}

// ---------------- argmax ----------------
__global__ void argmax_kernel(const float* __restrict__ soft, int* __restrict__ out) {
    int t = blockIdx.x * blockDim.x + threadIdx.x;
    if (t < T_LEN) {
        const float* s = soft + t * V_DIM;
        int best = 0;
        float bv = s[0];
        #pragma unroll
        for (int vv = 1; vv < V_DIM; vv++) {
            float v = s[vv];
            if (v > bv) { bv = v; best = vv; }
        }
        out[t] = best;
    }
}

// ================= fallback kernels (fp32, if ws too small) =================
__global__ __launch_bounds__(256) void rms_kernel(const float* __restrict__ x,
                                                  const float* __restrict__ w,
                                                  float* __restrict__ out) {
    int t = blockIdx.x;
    const float* xr = x + (size_t)t * D_DIM;
    float ss = 0.f;
    for (int d = threadIdx.x; d < D_DIM; d += 256) { float v = xr[d]; ss += v * v; }
    __shared__ float red[4];
    int lane = threadIdx.x & 63, wave = threadIdx.x >> 6;
    for (int off = 32; off > 0; off >>= 1) ss += __shfl_xor(ss, off);
    if (lane == 0) red[wave] = ss;
    __syncthreads();
    ss = red[0] + red[1] + red[2] + red[3];
    float r = 1.0f / sqrtf(ss * (1.0f / D_DIM) + 1e-6f);
    for (int d = threadIdx.x; d < D_DIM; d += 256) out[(size_t)t * D_DIM + d] = xr[d] * r * w[d];
}

__global__ __launch_bounds__(256) void embed_kernel(const float* __restrict__ soft,
                                                    const float* __restrict__ E,
                                                    float* __restrict__ x) {
    int t = blockIdx.x;
    __shared__ float srow[V_DIM];
    if (threadIdx.x < V_DIM) srow[threadIdx.x] = soft[t * V_DIM + threadIdx.x];
    __syncthreads();
    for (int d = threadIdx.x; d < D_DIM; d += 256) {
        float acc = 0.f;
        #pragma unroll
        for (int v = 0; v < V_DIM; v++) acc += srow[v] * E[v * D_DIM + d];
        x[(size_t)t * D_DIM + d] = acc;
    }
}

__global__ __launch_bounds__(256) void gemm_kernel(const float* __restrict__ A,
                                                   const float* __restrict__ B,
                                                   float* __restrict__ C,
                                                   int M, int N, int K,
                                                   float alpha, int accumulate) {
    const int BM = 64, BN = 64, BK = 16;
    __shared__ float As[BK][BM];
    __shared__ float Bsh[BK][BN];
    int tid = threadIdx.x;
    int tx = tid % 16, ty = tid / 16;
    int row0 = blockIdx.y * BM, col0 = blockIdx.x * BN;
    float acc[4][4] = {};
    for (int k0 = 0; k0 < K; k0 += BK) {
        #pragma unroll
        for (int i = 0; i < 4; i++) {
            int e = tid * 4 + i;
            int m = e / BK, kk = e % BK;
            int gr = row0 + m, gk = k0 + kk;
            As[kk][m] = (gr < M && gk < K) ? A[(size_t)gr * K + gk] : 0.f;
        }
        #pragma unroll
        for (int i = 0; i < 4; i++) {
            int e = tid * 4 + i;
            int kk = e / BN, n = e % BN;
            int gk = k0 + kk, gc = col0 + n;
            Bsh[kk][n] = (gk < K && gc < N) ? B[(size_t)gk * N + gc] : 0.f;
        }
        __syncthreads();
        #pragma unroll
        for (int kk = 0; kk < BK; kk++) {
            float a[4], b[4];
            #pragma unroll
            for (int i = 0; i < 4; i++) a[i] = As[kk][ty * 4 + i];
            #pragma unroll
            for (int j = 0; j < 4; j++) b[j] = Bsh[kk][tx * 4 + j];
            #pragma unroll
            for (int i = 0; i < 4; i++)
                #pragma unroll
                for (int j = 0; j < 4; j++)
                    acc[i][j] += a[i] * b[j];
        }
        __syncthreads();
    }
    #pragma unroll
    for (int i = 0; i < 4; i++) {
        int r = row0 + ty * 4 + i;
        if (r >= M) continue;
        #pragma unroll
        for (int j = 0; j < 4; j++) {
            int c = col0 + tx * 4 + j;
            if (c >= N) continue;
            size_t idx = (size_t)r * N + c;
            float val = alpha * acc[i][j];
            if (accumulate) val += C[idx];
            C[idx] = val;
        }
    }
}

__global__ __launch_bounds__(256) void attn_kernel(const float* __restrict__ q,
                                                   const float* __restrict__ k,
                                                   const float* __restrict__ v,
                                                   float* __restrict__ ctx) {
    int qi = blockIdx.x;
    int hh = blockIdx.y;
    __shared__ float sc[T_LEN];
    __shared__ float qrow[DH_DIM];
    __shared__ float red[8];
    __shared__ float part[4][DH_DIM];
    int tid = threadIdx.x;
    int lane = tid & 63, wave = tid >> 6;
    const float* qp = q + (size_t)qi * D_DIM + hh * DH_DIM;
    if (tid < DH_DIM) qrow[tid] = qp[tid];
    __syncthreads();
    const float scale = 0.125f;
    for (int j = wave; j <= qi; j += 4) {
        const float* kp = k + (size_t)j * D_DIM + hh * DH_DIM;
        float p = qrow[lane] * kp[lane];
        for (int off = 32; off > 0; off >>= 1) p += __shfl_xor(p, off);
        if (lane == 0) sc[j] = p * scale;
    }
    __syncthreads();
    int n = qi + 1;
    float m = -1e30f;
    for (int j = tid; j < n; j += 256) m = fmaxf(m, sc[j]);
    for (int off = 32; off > 0; off >>= 1) m = fmaxf(m, __shfl_xor(m, off));
    if (lane == 0) red[wave] = m;
    __syncthreads();
    m = fmaxf(fmaxf(red[0], red[1]), fmaxf(red[2], red[3]));
    float s = 0.f;
    for (int j = tid; j < n; j += 256) { float e = expf(sc[j] - m); sc[j] = e; s += e; }
    for (int off = 32; off > 0; off >>= 1) s += __shfl_xor(s, off);
    if (lane == 0) red[4 + wave] = s;
    __syncthreads();
    s = red[4] + red[5] + red[6] + red[7];
    float inv = 1.0f / s;
    float acc = 0.f;
    for (int j = wave; j < n; j += 4) {
        acc += sc[j] * v[(size_t)j * D_DIM + hh * DH_DIM + lane];
    }
    part[wave][lane] = acc;
    __syncthreads();
    if (tid < DH_DIM) {
        float r = (part[0][tid] + part[1][tid] + part[2][tid] + part[3][tid]) * inv;
        ctx[(size_t)qi * D_DIM + hh * DH_DIM + tid] = r;
    }
}

__global__ void silu_mul_kernel(const float* __restrict__ g, const float* __restrict__ u,
                                float* __restrict__ out, int nelem) {
    int i = blockIdx.x * blockDim.x + threadIdx.x;
    if (i < nelem) {
        float gv = g[i];
        float sg = 1.0f / (1.0f + expf(-gv));
        out[i] = gv * sg * u[i];
    }
}

static inline void launch_gemm(const float* A, const float* B, float* C,
                               int M, int N, int K, float alpha, int accumulate,
                               hipStream_t stream) {
    dim3 grid((N + 63) / 64, (M + 63) / 64);
    gemm_kernel<<<grid, 256, 0, stream>>>(A, B, C, M, N, K, alpha, accumulate);
}

// =====================================================================================
extern "C" void kernel_launch(void* const* d_in, const int* in_sizes, int n_in,
                              void* d_out, int out_size, void* d_ws, size_t ws_size,
                              hipStream_t stream) {
    const int* packed = (const int*)d_in[0];
    const float* E  = (const float*)d_in[6];
    const float* Wsrc[7] = {(const float*)d_in[7],  (const float*)d_in[10], (const float*)d_in[13],
                            (const float*)d_in[16], (const float*)d_in[19], (const float*)d_in[22],
                            (const float*)d_in[25]};
    const float* Asrc[7] = {(const float*)d_in[8],  (const float*)d_in[11], (const float*)d_in[14],
                            (const float*)d_in[17], (const float*)d_in[20], (const float*)d_in[23],
                            (const float*)d_in[26]};
    const float* Bsrc[7] = {(const float*)d_in[9],  (const float*)d_in[12], (const float*)d_in[15],
                            (const float*)d_in[18], (const float*)d_in[21], (const float*)d_in[24],
                            (const float*)d_in[27]};
    const float* ln1 = (const float*)d_in[28];
    const float* ln2 = (const float*)d_in[29];
    const float* lnf = (const float*)d_in[30];

    const size_t DD = (size_t)D_DIM * D_DIM;     // 1M
    const size_t DF = (size_t)D_DIM * F_DIM;     // 4M
    const size_t wsizes[7] = {DD, DD, DD, DD, DF, DF, DF};
    const int Kdim[7] = {D_DIM, D_DIM, D_DIM, D_DIM, D_DIM, D_DIM, F_DIM};
    const int Ndim[7] = {D_DIM, D_DIM, D_DIM, D_DIM, F_DIM, F_DIM, D_DIM};

    size_t u16_elems = 0;
    for (int p = 0; p < 7; p++) u16_elems += 2ull * N_LAYERS * wsizes[p];  // folded hi/lo
    u16_elems += 2ull * DD;            // h hi/lo
    u16_elems += 2ull * DD;            // ctx hi/lo
    u16_elems += 2ull * DF;            // ff hi/lo
    u16_elems += 6ull * DD;            // q,k,v hi/lo
    size_t f32_elems = (size_t)T_LEN * V_DIM + DD + 8 * DD;   // soft, x, 8-slot pool
    size_t need = u16_elems * 2 + f32_elems * 4 + 256;

    if (ws_size >= need) {
        ushort_t* ub = (ushort_t*)d_ws;
        size_t uo = 0;
        ushort_t *Whi[7], *Wlo[7];
        for (int p = 0; p < 7; p++) {
            Whi[p] = ub + uo; uo += (size_t)N_LAYERS * wsizes[p];
            Wlo[p] = ub + uo; uo += (size_t)N_LAYERS * wsizes[p];
        }
        ushort_t* h_hi = ub + uo; uo += DD;
        ushort_t* h_lo = ub + uo; uo += DD;
        ushort_t* c_hi = ub + uo; uo += DD;
        ushort_t* c_lo = ub + uo; uo += DD;
        ushort_t* f_hi = ub + uo; uo += DF;
        ushort_t* f_lo = ub + uo; uo += DF;
        ushort_t* qbh = ub + uo; uo += DD;
        ushort_t* qbl = ub + uo; uo += DD;
        ushort_t* kbh = ub + uo; uo += DD;
        ushort_t* kbl = ub + uo; uo += DD;
        ushort_t* vbh = ub + uo; uo += DD;
        ushort_t* vbl = ub + uo; uo += DD;
        float* fb = (float*)(ub + uo);
        size_t fo = 0;
        float* soft = fb + fo; fo += (size_t)T_LEN * V_DIM;
        float* x    = fb + fo; fo += DD;
        float* P    = fb + fo;   // 8-slot DD pool (= 2 DF slots)

        // fold weights (batched over layers)
        for (int p = 0; p < 7; p++) {
            dim3 grid(Ndim[p] / 64, Kdim[p] / 64, N_LAYERS);
            fold_kernel<<<grid, 256, 0, stream>>>(Wsrc[p], Asrc[p], Bsrc[p],
                                                  Whi[p], Wlo[p], Kdim[p], Ndim[p]);
        }

        init_soft_kernel<<<(T_LEN * V_DIM + 255) / 256, 256, 0, stream>>>(soft);

        const int n4 = (int)(DD / 4);
        GemmJob jz = {};

        for (int step = 0; step < N_STEPS; step++) {
            embed_rms_split_kernel<<<T_LEN, 256, 0, stream>>>(soft, E, ln1, x, h_hi, h_lo);
            for (int l = 0; l < N_LAYERS; l++) {
                {   // fused QKV, split-K x2: 384 blocks, 16 k-iters each
                    GemmJob jq = {Whi[0] + l * DD, Wlo[0] + l * DD, P,          nullptr, nullptr, 0, D_DIM};
                    GemmJob jk = {Whi[1] + l * DD, Wlo[1] + l * DD, P + 2 * DD, nullptr, nullptr, 0, D_DIM};
                    GemmJob jv = {Whi[2] + l * DD, Wlo[2] + l * DD, P + 4 * DD, nullptr, nullptr, 0, D_DIM};
                    gemm128_kernel<<<dim3(8, 8, 6), 256, 0, stream>>>(
                        h_hi, h_lo, D_DIM, D_DIM, 2, jq, jk, jv, jz, jz, jz, jz, jz);
                    qkv_sum_split_kernel<<<(int)(DD / 4 / 256), 256, 0, stream>>>(
                        P, 2, qbh, qbl, kbh, kbl, vbh, vbl);
                }
                attn_mfma_kernel<<<dim3(T_LEN / 64, H_NUM), 256, 0, stream>>>(
                    qbh, qbl, kbh, kbl, vbh, vbl, c_hi, c_lo);
                {   // o-proj split-K x4 (256 blocks, 8 iters) + fused add + rms(ln2[l])
                    GemmJob jo = {Whi[3] + l * DD, Wlo[3] + l * DD, P, nullptr, nullptr, 0, D_DIM};
                    gemm128_kernel<<<dim3(8, 8, 4), 256, 0, stream>>>(
                        c_hi, c_lo, D_DIM, D_DIM, 4, jo, jz, jz, jz, jz, jz, jz, jz);
                    add_rms_split_kernel<<<T_LEN, 256, 0, stream>>>(
                        x, P, 4, ln2 + (size_t)l * D_DIM, h_hi, h_lo);
                }
                {   // G,U (512 blocks, 32 iters)
                    GemmJob jg = {Whi[4] + l * DF, Wlo[4] + l * DF, P,      nullptr, nullptr, 0, D_DIM};
                    GemmJob ju = {Whi[5] + l * DF, Wlo[5] + l * DF, P + DF, nullptr, nullptr, 0, D_DIM};
                    gemm128_kernel<<<dim3(32, 8, 2), 256, 0, stream>>>(
                        h_hi, h_lo, D_DIM, F_DIM, 1, jg, ju, jz, jz, jz, jz, jz, jz);
                    silu_sum_split_kernel<<<(int)(DF / 4 / 256), 256, 0, stream>>>(
                        P, 1, f_hi, f_lo);
                }
                {   // d-proj split-K x8 (512 blocks, 16 iters)
                    GemmJob jd = {Whi[6] + l * DF, Wlo[6] + l * DF, P, nullptr, nullptr, 0, F_DIM};
                    gemm128_kernel<<<dim3(8, 8, 8), 256, 0, stream>>>(
                        f_hi, f_lo, F_DIM, D_DIM, 8, jd, jz, jz, jz, jz, jz, jz, jz);
                    if (l + 1 < N_LAYERS) {
                        add_rms_split_kernel<<<T_LEN, 256, 0, stream>>>(
                            x, P, 8, ln1 + (size_t)(l + 1) * D_DIM, h_hi, h_lo);
                    } else {
                        addn_kernel<<<(n4 + 255) / 256, 256, 0, stream>>>(x, P, 8, n4);
                    }
                }
            }
            head_kernel<<<T_LEN, 256, 0, stream>>>(x, lnf, E, packed, soft);
        }
        argmax_kernel<<<(T_LEN + 255) / 256, 256, 0, stream>>>(soft, (int*)d_out);
        return;
    }

    // -------- fallback: fp32 path --------
    float* ws = (float*)d_ws;
    size_t off = 0;
    float* soft = ws + off; off += (size_t)T_LEN * V_DIM;
    float* x    = ws + off; off += (size_t)T_LEN * D_DIM;
    float* h    = ws + off; off += (size_t)T_LEN * D_DIM;
    float* qb   = ws + off; off += (size_t)T_LEN * D_DIM;
    float* kb   = ws + off; off += (size_t)T_LEN * D_DIM;
    float* vb   = ws + off; off += (size_t)T_LEN * D_DIM;
    float* cb   = ws + off; off += (size_t)T_LEN * D_DIM;
    float* gb   = ws + off; off += (size_t)T_LEN * F_DIM;
    float* ubf  = ws + off; off += (size_t)T_LEN * F_DIM;
    float* tmp  = ws + off; off += (size_t)T_LEN * R_LORA;

    init_soft_kernel<<<(T_LEN * V_DIM + 255) / 256, 256, 0, stream>>>(soft);
    for (int step = 0; step < N_STEPS; step++) {
        embed_kernel<<<T_LEN, 256, 0, stream>>>(soft, E, x);
        for (int l = 0; l < N_LAYERS; l++) {
            const float* ln1_l = ln1 + (size_t)l * D_DIM;
            const float* ln2_l = ln2 + (size_t)l * D_DIM;
            rms_kernel<<<T_LEN, 256, 0, stream>>>(x, ln1_l, h);
            launch_gemm(h, Asrc[0] + (size_t)l * D_DIM * R_LORA, tmp, T_LEN, R_LORA, D_DIM, 1.0f, 0, stream);
            launch_gemm(h, Wsrc[0] + (size_t)l * DD, qb, T_LEN, D_DIM, D_DIM, 1.0f, 0, stream);
            launch_gemm(tmp, Bsrc[0] + (size_t)l * R_LORA * D_DIM, qb, T_LEN, D_DIM, R_LORA, LORA_SCALE, 1, stream);
            launch_gemm(h, Asrc[1] + (size_t)l * D_DIM * R_LORA, tmp, T_LEN, R_LORA, D_DIM, 1.0f, 0, stream);
            launch_gemm(h, Wsrc[1] + (size_t)l * DD, kb, T_LEN, D_DIM, D_DIM, 1.0f, 0, stream);
            launch_gemm(tmp, Bsrc[1] + (size_t)l * R_LORA * D_DIM, kb, T_LEN, D_DIM, R_LORA, LORA_SCALE, 1, stream);
            launch_gemm(h, Asrc[2] + (size_t)l * D_DIM * R_LORA, tmp, T_LEN, R_LORA, D_DIM, 1.0f, 0, stream);
            launch_gemm(h, Wsrc[2] + (size_t)l * DD, vb, T_LEN, D_DIM, D_DIM, 1.0f, 0, stream);
            launch_gemm(tmp, Bsrc[2] + (size_t)l * R_LORA * D_DIM, vb, T_LEN, D_DIM, R_LORA, LORA_SCALE, 1, stream);
            attn_kernel<<<dim3(T_LEN, H_NUM), 256, 0, stream>>>(qb, kb, vb, cb);
            launch_gemm(cb, Asrc[3] + (size_t)l * D_DIM * R_LORA, tmp, T_LEN, R_LORA, D_DIM, 1.0f, 0, stream);
            launch_gemm(cb, Wsrc[3] + (size_t)l * DD, x, T_LEN, D_DIM, D_DIM, 1.0f, 1, stream);
            launch_gemm(tmp, Bsrc[3] + (size_t)l * R_LORA * D_DIM, x, T_LEN, D_DIM, R_LORA, LORA_SCALE, 1, stream);
            rms_kernel<<<T_LEN, 256, 0, stream>>>(x, ln2_l, h);
            launch_gemm(h, Asrc[4] + (size_t)l * D_DIM * R_LORA, tmp, T_LEN, R_LORA, D_DIM, 1.0f, 0, stream);
            launch_gemm(h, Wsrc[4] + (size_t)l * DF, gb, T_LEN, F_DIM, D_DIM, 1.0f, 0, stream);
            launch_gemm(tmp, Bsrc[4] + (size_t)l * R_LORA * F_DIM, gb, T_LEN, F_DIM, R_LORA, LORA_SCALE, 1, stream);
            launch_gemm(h, Asrc[5] + (size_t)l * D_DIM * R_LORA, tmp, T_LEN, R_LORA, D_DIM, 1.0f, 0, stream);
            launch_gemm(h, Wsrc[5] + (size_t)l * DF, ubf, T_LEN, F_DIM, D_DIM, 1.0f, 0, stream);
            launch_gemm(tmp, Bsrc[5] + (size_t)l * R_LORA * F_DIM, ubf, T_LEN, F_DIM, R_LORA, LORA_SCALE, 1, stream);
            silu_mul_kernel<<<(T_LEN * F_DIM + 255) / 256, 256, 0, stream>>>(gb, ubf, gb, T_LEN * F_DIM);
            launch_gemm(gb, Asrc[6] + (size_t)l * F_DIM * R_LORA, tmp, T_LEN, R_LORA, F_DIM, 1.0f, 0, stream);
            launch_gemm(gb, Wsrc[6] + (size_t)l * DF, x, T_LEN, D_DIM, F_DIM, 1.0f, 1, stream);
            launch_gemm(tmp, Bsrc[6] + (size_t)l * R_LORA * D_DIM, x, T_LEN, D_DIM, R_LORA, LORA_SCALE, 1, stream);
        }
        head_kernel<<<T_LEN, 256, 0, stream>>>(x, lnf, E, packed, soft);
    }
    argmax_kernel<<<(T_LEN + 255) / 256, 256, 0, stream>>>(soft, (int*)d_out);
}

// Round 9
// 1028.055 us; speedup vs baseline: 1.1684x; 1.0058x over previous
//
#include <hip/hip_runtime.h>
#include <hip/hip_bf16.h>

#define T_LEN 1024
#define D_DIM 1024
#define V_DIM 17
#define H_NUM 16
#define DH_DIM 64
#define F_DIM 4096
#define R_LORA 32
#define N_LAYERS 2
#define N_STEPS 2
#define MASK_ID 16
#define LORA_SCALE 2.0f

typedef __attribute__((ext_vector_type(8))) short bfx8;   // 8 bf16 in 4 VGPRs
typedef __attribute__((ext_vector_type(4))) float f32x4;

typedef unsigned short ushort_t;
typedef unsigned int uint_t;

#define AS1 __attribute__((address_space(1)))
#define AS3 __attribute__((address_space(3)))

__device__ __forceinline__ void gload16(const ushort_t* g, ushort_t* l) {
    __builtin_amdgcn_global_load_lds((const AS1 void*)(const void*)g,
                                     (AS3 void*)(void*)l, 16, 0, 0);
}

__device__ __forceinline__ ushort_t f2bf(float v) {
    __hip_bfloat16 h = __float2bfloat16(v);
    return __builtin_bit_cast(unsigned short, h);
}
__device__ __forceinline__ float bf2f(ushort_t u) {
    return __uint_as_float(((uint_t)u) << 16);
}
__device__ __forceinline__ void split4_store(float y0, float y1, float y2, float y3,
                                             ushort_t* __restrict__ hi, ushort_t* __restrict__ lo,
                                             size_t idx) {
    ushort_t h0 = f2bf(y0), h1 = f2bf(y1), h2 = f2bf(y2), h3 = f2bf(y3);
    ushort_t l0 = f2bf(y0 - bf2f(h0));
    ushort_t l1 = f2bf(y1 - bf2f(h1));
    ushort_t l2 = f2bf(y2 - bf2f(h2));
    ushort_t l3 = f2bf(y3 - bf2f(h3));
    uint2 hv, lv;
    hv.x = (uint_t)h0 | ((uint_t)h1 << 16);
    hv.y = (uint_t)h2 | ((uint_t)h3 << 16);
    lv.x = (uint_t)l0 | ((uint_t)l1 << 16);
    lv.y = (uint_t)l2 | ((uint_t)l3 << 16);
    *(uint2*)(hi + idx) = hv;
    *(uint2*)(lo + idx) = lv;
}

// ---------------- init soft ----------------
__global__ void init_soft_kernel(float* __restrict__ soft) {
    int idx = blockIdx.x * blockDim.x + threadIdx.x;
    if (idx < T_LEN * V_DIM) {
        soft[idx] = ((idx % V_DIM) == MASK_ID) ? 1.0f : 0.0f;
    }
}

// ---------------- fused embed + rms + split ----------------
__global__ __launch_bounds__(256) void embed_rms_split_kernel(
    const float* __restrict__ soft, const float* __restrict__ E,
    const float* __restrict__ w, float* __restrict__ x,
    ushort_t* __restrict__ hi, ushort_t* __restrict__ lo)
{
    const int t = blockIdx.x, tid = threadIdx.x;
    __shared__ float srow[V_DIM];
    __shared__ float red[4];
    if (tid < V_DIM) srow[tid] = soft[t * V_DIM + tid];
    __syncthreads();
    const int d0 = tid * 4;
    float4 acc = {0.f, 0.f, 0.f, 0.f};
    #pragma unroll
    for (int v = 0; v < V_DIM; v++) {
        float s = srow[v];
        float4 e = *(const float4*)(E + (size_t)v * D_DIM + d0);
        acc.x = fmaf(s, e.x, acc.x);
        acc.y = fmaf(s, e.y, acc.y);
        acc.z = fmaf(s, e.z, acc.z);
        acc.w = fmaf(s, e.w, acc.w);
    }
    size_t base = (size_t)t * D_DIM + d0;
    *(float4*)(x + base) = acc;
    float ss = acc.x * acc.x + acc.y * acc.y + acc.z * acc.z + acc.w * acc.w;
    const int lane = tid & 63, wv = tid >> 6;
    #pragma unroll
    for (int off = 32; off > 0; off >>= 1) ss += __shfl_xor(ss, off);
    if (lane == 0) red[wv] = ss;
    __syncthreads();
    ss = red[0] + red[1] + red[2] + red[3];
    const float r = 1.0f / sqrtf(ss * (1.0f / D_DIM) + 1e-6f);
    const float4 wv4 = *(const float4*)(w + d0);
    split4_store(acc.x * r * wv4.x, acc.y * r * wv4.y, acc.z * r * wv4.z, acc.w * r * wv4.w,
                 hi, lo, base);
}

// ---------------- fold v3: out^T = split(W + 2*A@B) ----------------
__global__ __launch_bounds__(256) void fold_kernel(
    const float* __restrict__ W,   // [L,K,N]
    const float* __restrict__ A,   // [L,K,R]
    const float* __restrict__ Bm,  // [L,R,N]
    ushort_t* __restrict__ oHi,    // [L,N,K]
    ushort_t* __restrict__ oLo,
    int K, int N)
{
    const int l = blockIdx.z;
    W   += (size_t)l * K * N;
    A   += (size_t)l * K * R_LORA;
    Bm  += (size_t)l * R_LORA * N;
    oHi += (size_t)l * K * N;
    oLo += (size_t)l * K * N;
    __shared__ float Als[64][R_LORA + 1];
    __shared__ uint_t tile[64][65];
    const int tid = threadIdx.x;
    const int n0 = blockIdx.x * 64, k0 = blockIdx.y * 64;

    {
        const int row = tid >> 2, c0 = (tid & 3) * 8;
        const float* src = A + (size_t)(k0 + row) * R_LORA + c0;
        float4 a0 = *(const float4*)(src);
        float4 a1 = *(const float4*)(src + 4);
        Als[row][c0 + 0] = a0.x; Als[row][c0 + 1] = a0.y;
        Als[row][c0 + 2] = a0.z; Als[row][c0 + 3] = a0.w;
        Als[row][c0 + 4] = a1.x; Als[row][c0 + 5] = a1.y;
        Als[row][c0 + 6] = a1.z; Als[row][c0 + 7] = a1.w;
    }
    const int nl = tid & 63, kq = tid >> 6;
    float wreg[16];
    #pragma unroll
    for (int i = 0; i < 16; i++)
        wreg[i] = W[(size_t)(k0 + kq * 16 + i) * N + n0 + nl];
    float breg[R_LORA];
    #pragma unroll
    for (int r = 0; r < R_LORA; r++) breg[r] = Bm[(size_t)r * N + n0 + nl];
    __syncthreads();
    #pragma unroll
    for (int i = 0; i < 16; i++) {
        const int kl = kq * 16 + i;
        float acc = 0.f;
        #pragma unroll
        for (int r = 0; r < R_LORA; r++) acc = fmaf(Als[kl][r], breg[r], acc);
        float val = wreg[i] + LORA_SCALE * acc;
        ushort_t h = f2bf(val);
        tile[kl][nl] = ((uint_t)h << 16) | (uint_t)f2bf(val - bf2f(h));
    }
    __syncthreads();
    {
        const int nl2 = tid >> 2;
        const int kc0 = (tid & 3) * 16;
        ushort_t hb[16], lb[16];
        #pragma unroll
        for (int i = 0; i < 16; i++) {
            uint_t pk = tile[kc0 + i][nl2];
            hb[i] = (ushort_t)(pk >> 16);
            lb[i] = (ushort_t)(pk & 0xffffu);
        }
        size_t idx = (size_t)(n0 + nl2) * K + k0 + kc0;
        *(uint4*)(oHi + idx)     = *(uint4*)&hb[0];
        *(uint4*)(oHi + idx + 8) = *(uint4*)&hb[8];
        *(uint4*)(oLo + idx)     = *(uint4*)&lb[0];
        *(uint4*)(oLo + idx + 8) = *(uint4*)&lb[8];
    }
}

// ---------------- 128x128 MFMA split-bf16 GEMM, 2-phase + COUNTED vmcnt (T3+T4) ----------------
// stage(next) -> s_waitcnt vmcnt(8) (cur's loads only; next's 8 stay in flight
// across BOTH barriers and the MFMA phase) -> raw s_barrier -> compute -> s_barrier.
struct GemmJob {
    const ushort_t* Bh;
    const ushort_t* Bl;
    float* Cf;        // if non-null: f32 store (partials: slot s at Cf + s*T_LEN*N)
    ushort_t* Ch;     // else split store (kslices must be 1)
    ushort_t* Cl;
    int k0, k1;
};

__global__ __launch_bounds__(256) void gemm128_kernel(
    const ushort_t* __restrict__ Ahi, const ushort_t* __restrict__ Alo,
    int K, int N, int kslices,
    GemmJob j0, GemmJob j1, GemmJob j2, GemmJob j3,
    GemmJob j4, GemmJob j5, GemmJob j6, GemmJob j7)
{
    GemmJob jb;
    int s;
    {
        const int z = blockIdx.z;
        const int ji = z / kslices;
        s = z - ji * kslices;
        if      (ji == 0) jb = j0; else if (ji == 1) jb = j1;
        else if (ji == 2) jb = j2; else if (ji == 3) jb = j3;
        else if (ji == 4) jb = j4; else if (ji == 5) jb = j5;
        else if (ji == 6) jb = j6; else jb = j7;
    }
    const int klen = (jb.k1 - jb.k0) / kslices;
    const int myk0 = jb.k0 + s * klen;
    const int myk1 = myk0 + klen;
    float* Cf = jb.Cf ? jb.Cf + (size_t)s * T_LEN * (size_t)N : nullptr;

    __shared__ ushort_t Ash[2][128][32];
    __shared__ ushort_t Asl[2][128][32];
    __shared__ ushort_t Bsh[2][128][32];
    __shared__ ushort_t Bsl[2][128][32];

    const int tid = threadIdx.x, lane = tid & 63, w = tid >> 6;
    const int l15 = lane & 15, lg = lane >> 4;
    const int m0 = blockIdx.y * 128, n0 = blockIdx.x * 128;
    const int wm = (w >> 1) * 64, wn = (w & 1) * 64;

    const int r0 = w * 32;
    const int rsub = lane >> 2;
    const int cs = lane & 3;
    const int csl = (cs ^ ((rsub >> 1) & 3)) * 8;   // pre-swizzled source col (shorts)
    const int rsl = (lg ^ ((l15 >> 1) & 3)) * 8;    // swizzled read col (shorts)

    f32x4 acc[4][4];
    #pragma unroll
    for (int i = 0; i < 4; i++)
        #pragma unroll
        for (int j = 0; j < 4; j++) acc[i][j] = f32x4{0.f, 0.f, 0.f, 0.f};

    const size_t rowA = (size_t)(m0 + r0 + rsub) * K;
    const size_t rowB = (size_t)(n0 + r0 + rsub) * K;
    const size_t rstep = (size_t)16 * K;

    auto stage = [&](int b, int kk) {
        const ushort_t* a0 = Ahi + rowA + kk + csl;
        const ushort_t* a1 = Alo + rowA + kk + csl;
        const ushort_t* b0 = jb.Bh + rowB + kk + csl;
        const ushort_t* b1 = jb.Bl + rowB + kk + csl;
        gload16(a0,         &Ash[b][r0][0]);
        gload16(a0 + rstep, &Ash[b][r0 + 16][0]);
        gload16(a1,         &Asl[b][r0][0]);
        gload16(a1 + rstep, &Asl[b][r0 + 16][0]);
        gload16(b0,         &Bsh[b][r0][0]);
        gload16(b0 + rstep, &Bsh[b][r0 + 16][0]);
        gload16(b1,         &Bsl[b][r0][0]);
        gload16(b1 + rstep, &Bsl[b][r0 + 16][0]);
    };

    stage(0, myk0);               // prologue: 8 loads in flight
    int cur = 0;
    for (int kk = myk0; kk < myk1; kk += 32) {
        __builtin_amdgcn_sched_barrier(0);
        const bool has_next = (kk + 32 < myk1);
        if (has_next) {
            stage(cur ^ 1, kk + 32);                       // 16 outstanding
            asm volatile("s_waitcnt vmcnt(8)" ::: "memory");  // wait cur's 8 only
        } else {
            asm volatile("s_waitcnt vmcnt(0)" ::: "memory");  // last tile: full drain
        }
        __builtin_amdgcn_s_barrier();      // all waves: cur staged
        __builtin_amdgcn_sched_barrier(0);
        bfx8 bh[4], bl[4];
        #pragma unroll
        for (int ni = 0; ni < 4; ni++) {
            bh[ni] = *(const bfx8*)&Bsh[cur][wn + ni * 16 + l15][rsl];
            bl[ni] = *(const bfx8*)&Bsl[cur][wn + ni * 16 + l15][rsl];
        }
        #pragma unroll
        for (int mi = 0; mi < 4; mi++) {
            bfx8 ah = *(const bfx8*)&Ash[cur][wm + mi * 16 + l15][rsl];
            bfx8 al = *(const bfx8*)&Asl[cur][wm + mi * 16 + l15][rsl];
            #pragma unroll
            for (int ni = 0; ni < 4; ni++) {
                acc[mi][ni] = __builtin_amdgcn_mfma_f32_16x16x32_bf16(ah, bh[ni], acc[mi][ni], 0, 0, 0);
                acc[mi][ni] = __builtin_amdgcn_mfma_f32_16x16x32_bf16(ah, bl[ni], acc[mi][ni], 0, 0, 0);
                acc[mi][ni] = __builtin_amdgcn_mfma_f32_16x16x32_bf16(al, bh[ni], acc[mi][ni], 0, 0, 0);
            }
        }
        __builtin_amdgcn_sched_barrier(0);
        __builtin_amdgcn_s_barrier();      // all waves done reading cur (safe to overwrite next iter)
        cur ^= 1;
    }

    if (Cf) {
        #pragma unroll
        for (int mi = 0; mi < 4; mi++)
            #pragma unroll
            for (int ni = 0; ni < 4; ni++) {
                int col = n0 + wn + ni * 16 + l15;
                #pragma unroll
                for (int i = 0; i < 4; i++) {
                    int row = m0 + wm + mi * 16 + lg * 4 + i;
                    Cf[(size_t)row * N + col] = acc[mi][ni][i];
                }
            }
    } else {
        #pragma unroll
        for (int mi = 0; mi < 4; mi++)
            #pragma unroll
            for (int ni = 0; ni < 4; ni++) {
                int col = n0 + wn + ni * 16 + l15;
                #pragma unroll
                for (int i = 0; i < 4; i++) {
                    int row = m0 + wm + mi * 16 + lg * 4 + i;
                    size_t idx = (size_t)row * N + col;
                    float v = acc[mi][ni][i];
                    ushort_t h = f2bf(v);
                    jb.Ch[idx] = h;
                    jb.Cl[idx] = f2bf(v - bf2f(h));
                }
            }
    }
}

// ---------------- qkv epilogue: q/k/v = split(sum of S partials each) ----------------
__global__ __launch_bounds__(256) void qkv_sum_split_kernel(
    const float* __restrict__ P, int S,
    ushort_t* __restrict__ qbh, ushort_t* __restrict__ qbl,
    ushort_t* __restrict__ kbh, ushort_t* __restrict__ kbl,
    ushort_t* __restrict__ vbh, ushort_t* __restrict__ vbl)
{
    const size_t DD1 = (size_t)T_LEN * D_DIM;
    size_t e = ((size_t)blockIdx.x * 256 + threadIdx.x) * 4;
    float4 q = {0,0,0,0}, k = {0,0,0,0}, v = {0,0,0,0};
    for (int j = 0; j < S; j++) {
        float4 a = *(const float4*)(P + (size_t)j * DD1 + e);
        q.x += a.x; q.y += a.y; q.z += a.z; q.w += a.w;
        float4 b = *(const float4*)(P + (size_t)(S + j) * DD1 + e);
        k.x += b.x; k.y += b.y; k.z += b.z; k.w += b.w;
        float4 c = *(const float4*)(P + (size_t)(2 * S + j) * DD1 + e);
        v.x += c.x; v.y += c.y; v.z += c.z; v.w += c.w;
    }
    split4_store(q.x, q.y, q.z, q.w, qbh, qbl, e);
    split4_store(k.x, k.y, k.z, k.w, kbh, kbl, e);
    split4_store(v.x, v.y, v.z, v.w, vbh, vbl, e);
}

// ---------------- x += sum of nparts DD-sized partials ----------------
__global__ void addn_kernel(float* __restrict__ x, const float* __restrict__ P,
                            int nparts, int n4) {
    int i = blockIdx.x * blockDim.x + threadIdx.x;
    if (i < n4) {
        const size_t DD1 = (size_t)T_LEN * D_DIM;
        size_t e = (size_t)i * 4;
        float4 xv = *(const float4*)(x + e);
        for (int j = 0; j < nparts; j++) {
            float4 p = *(const float4*)(P + (size_t)j * DD1 + e);
            xv.x += p.x; xv.y += p.y; xv.z += p.z; xv.w += p.w;
        }
        *(float4*)(x + e) = xv;
    }
}

// ---------------- fused: x += sum(nparts); h = split(rms(x,w)) ----------------
__global__ __launch_bounds__(256) void add_rms_split_kernel(
    float* __restrict__ x, const float* __restrict__ P, int nparts,
    const float* __restrict__ w, ushort_t* __restrict__ hi, ushort_t* __restrict__ lo)
{
    const int t = blockIdx.x, tid = threadIdx.x;
    const size_t DD1 = (size_t)T_LEN * D_DIM;
    size_t base = (size_t)t * D_DIM + tid * 4;
    float4 xv = *(const float4*)(x + base);
    for (int j = 0; j < nparts; j++) {
        float4 p = *(const float4*)(P + (size_t)j * DD1 + base);
        xv.x += p.x; xv.y += p.y; xv.z += p.z; xv.w += p.w;
    }
    *(float4*)(x + base) = xv;
    float ss = xv.x * xv.x + xv.y * xv.y + xv.z * xv.z + xv.w * xv.w;
    __shared__ float red[4];
    const int lane = tid & 63, wv = tid >> 6;
    #pragma unroll
    for (int off = 32; off > 0; off >>= 1) ss += __shfl_xor(ss, off);
    if (lane == 0) red[wv] = ss;
    __syncthreads();
    ss = red[0] + red[1] + red[2] + red[3];
    const float r = 1.0f / sqrtf(ss * (1.0f / D_DIM) + 1e-6f);
    const float4 wv4 = *(const float4*)(w + tid * 4);
    split4_store(xv.x * r * wv4.x, xv.y * r * wv4.y, xv.z * r * wv4.z, xv.w * r * wv4.w,
                 hi, lo, base);
}

// ---------------- silu epilogue ----------------
__global__ void silu_sum_split_kernel(const float* __restrict__ P, int parts,
                                      ushort_t* __restrict__ hi, ushort_t* __restrict__ lo) {
    const size_t DF1 = (size_t)T_LEN * F_DIM;
    size_t e = ((size_t)blockIdx.x * 256 + threadIdx.x) * 4;
    float4 g = {0,0,0,0}, u = {0,0,0,0};
    for (int j = 0; j < parts; j++) {
        float4 a = *(const float4*)(P + (size_t)j * DF1 + e);
        g.x += a.x; g.y += a.y; g.z += a.z; g.w += a.w;
        float4 b = *(const float4*)(P + (size_t)(parts + j) * DF1 + e);
        u.x += b.x; u.y += b.y; u.z += b.z; u.w += b.w;
    }
    float y0 = g.x / (1.f + expf(-g.x)) * u.x;
    float y1 = g.y / (1.f + expf(-g.y)) * u.y;
    float y2 = g.z / (1.f + expf(-g.z)) * u.z;
    float y3 = g.w / (1.f + expf(-g.w)) * u.w;
    split4_store(y0, y1, y2, y3, hi, lo, e);
}

// ---------------- MFMA flash attention, T14 async-STAGE ----------------
#define KS_PAD 72
#define P_PAD 72
__global__ __launch_bounds__(256, 1) void attn_mfma_kernel(
    const ushort_t* __restrict__ qh, const ushort_t* __restrict__ ql,
    const ushort_t* __restrict__ kh, const ushort_t* __restrict__ kl,
    const ushort_t* __restrict__ vh, const ushort_t* __restrict__ vl,
    ushort_t* __restrict__ chi, ushort_t* __restrict__ clo)
{
    __shared__ ushort_t Ksh[64][KS_PAD];
    __shared__ ushort_t Ksl[64][KS_PAD];
    __shared__ ushort_t VTh[64][KS_PAD];
    __shared__ ushort_t VTl[64][KS_PAD];
    __shared__ ushort_t Ph[4][16][P_PAD];
    __shared__ ushort_t Pl[4][16][P_PAD];

    const int qt = blockIdx.x, hh = blockIdx.y;
    const int tid = threadIdx.x, w = tid >> 6, lane = tid & 63;
    const int l15 = lane & 15, lg = lane >> 4;
    const int q0 = qt * 64;
    const int hcol = hh * DH_DIM;

    bfx8 qa_h[2], qa_l[2];
    {
        size_t qrow = (size_t)(q0 + w * 16 + l15) * D_DIM + hcol;
        #pragma unroll
        for (int ks = 0; ks < 2; ks++) {
            qa_h[ks] = *(const bfx8*)(qh + qrow + ks * 32 + lg * 8);
            qa_l[ks] = *(const bfx8*)(ql + qrow + ks * 32 + lg * 8);
        }
    }

    f32x4 o[4];
    #pragma unroll
    for (int ni = 0; ni < 4; ni++) o[ni] = f32x4{0.f, 0.f, 0.f, 0.f};
    float mrun[4], lrun[4];
    #pragma unroll
    for (int i = 0; i < 4; i++) { mrun[i] = -3.0e38f; lrun[i] = 0.f; }

    const int srow = tid >> 2;
    const int sseg = (tid & 3) * 16;
    const int vp = tid & 31;
    const int vd0 = (tid >> 5) * 8;

    uint4 kh0, kh1, kl0, kl1, vh0, vh1, vl0, vl1;
    auto load_tile = [&](int kt) {
        size_t src = (size_t)(kt * 64 + srow) * D_DIM + hcol + sseg;
        kh0 = *(const uint4*)(kh + src);
        kh1 = *(const uint4*)(kh + src + 8);
        kl0 = *(const uint4*)(kl + src);
        kl1 = *(const uint4*)(kl + src + 8);
        size_t s0 = (size_t)(kt * 64 + 2 * vp) * D_DIM + hcol + vd0;
        vh0 = *(const uint4*)(vh + s0);
        vh1 = *(const uint4*)(vh + s0 + D_DIM);
        vl0 = *(const uint4*)(vl + s0);
        vl1 = *(const uint4*)(vl + s0 + D_DIM);
    };
    load_tile(0);

    for (int kt = 0; kt <= qt; kt++) {
        __syncthreads();
        {
            *(uint4*)&Ksh[srow][sseg]     = kh0;
            *(uint4*)&Ksh[srow][sseg + 8] = kh1;
            *(uint4*)&Ksl[srow][sseg]     = kl0;
            *(uint4*)&Ksl[srow][sseg + 8] = kl1;
            const ushort_t* a = (const ushort_t*)&vh0;
            const ushort_t* b = (const ushort_t*)&vh1;
            const ushort_t* c = (const ushort_t*)&vl0;
            const ushort_t* d = (const ushort_t*)&vl1;
            #pragma unroll
            for (int j = 0; j < 8; j++) {
                *(uint_t*)&VTh[vd0 + j][2 * vp] = (uint_t)a[j] | ((uint_t)b[j] << 16);
                *(uint_t*)&VTl[vd0 + j][2 * vp] = (uint_t)c[j] | ((uint_t)d[j] << 16);
            }
        }
        __syncthreads();
        if (kt < qt) load_tile(kt + 1);

        f32x4 s[4];
        #pragma unroll
        for (int ni = 0; ni < 4; ni++) s[ni] = f32x4{0.f, 0.f, 0.f, 0.f};
        #pragma unroll
        for (int ks = 0; ks < 2; ks++) {
            #pragma unroll
            for (int ni = 0; ni < 4; ni++) {
                bfx8 bh = *(const bfx8*)&Ksh[ni * 16 + l15][ks * 32 + lg * 8];
                bfx8 bl = *(const bfx8*)&Ksl[ni * 16 + l15][ks * 32 + lg * 8];
                s[ni] = __builtin_amdgcn_mfma_f32_16x16x32_bf16(qa_h[ks], bh, s[ni], 0, 0, 0);
                s[ni] = __builtin_amdgcn_mfma_f32_16x16x32_bf16(qa_h[ks], bl, s[ni], 0, 0, 0);
                s[ni] = __builtin_amdgcn_mfma_f32_16x16x32_bf16(qa_l[ks], bh, s[ni], 0, 0, 0);
            }
        }

        const int kbase = kt * 64;
        float rmax[4];
        #pragma unroll
        for (int i = 0; i < 4; i++) rmax[i] = -3.0e38f;
        #pragma unroll
        for (int ni = 0; ni < 4; ni++) {
            int kc = kbase + ni * 16 + l15;
            #pragma unroll
            for (int i = 0; i < 4; i++) {
                int qrow = q0 + w * 16 + lg * 4 + i;
                float v = s[ni][i] * 0.125f;
                v = (kc <= qrow) ? v : -3.0e38f;
                s[ni][i] = v;
                rmax[i] = fmaxf(rmax[i], v);
            }
        }
        #pragma unroll
        for (int off = 1; off < 16; off <<= 1) {
            #pragma unroll
            for (int i = 0; i < 4; i++) rmax[i] = fmaxf(rmax[i], __shfl_xor(rmax[i], off));
        }
        float psum[4];
        #pragma unroll
        for (int i = 0; i < 4; i++) {
            float nm = fmaxf(mrun[i], rmax[i]);
            float sc = __expf(mrun[i] - nm);
            lrun[i] *= sc;
            #pragma unroll
            for (int ni = 0; ni < 4; ni++) o[ni][i] *= sc;
            mrun[i] = nm;
            psum[i] = 0.f;
        }
        #pragma unroll
        for (int ni = 0; ni < 4; ni++) {
            #pragma unroll
            for (int i = 0; i < 4; i++) {
                float e = __expf(s[ni][i] - mrun[i]);
                s[ni][i] = e;
                psum[i] += e;
            }
        }
        #pragma unroll
        for (int off = 1; off < 16; off <<= 1) {
            #pragma unroll
            for (int i = 0; i < 4; i++) psum[i] += __shfl_xor(psum[i], off);
        }
        #pragma unroll
        for (int i = 0; i < 4; i++) lrun[i] += psum[i];

        #pragma unroll
        for (int ni = 0; ni < 4; ni++) {
            #pragma unroll
            for (int i = 0; i < 4; i++) {
                float e = s[ni][i];
                ushort_t hp = f2bf(e);
                Ph[w][lg * 4 + i][ni * 16 + l15] = hp;
                Pl[w][lg * 4 + i][ni * 16 + l15] = f2bf(e - bf2f(hp));
            }
        }
        #pragma unroll
        for (int ks = 0; ks < 2; ks++) {
            bfx8 ah = *(const bfx8*)&Ph[w][l15][ks * 32 + lg * 8];
            bfx8 al = *(const bfx8*)&Pl[w][l15][ks * 32 + lg * 8];
            #pragma unroll
            for (int ni = 0; ni < 4; ni++) {
                bfx8 bh = *(const bfx8*)&VTh[ni * 16 + l15][ks * 32 + lg * 8];
                bfx8 bl = *(const bfx8*)&VTl[ni * 16 + l15][ks * 32 + lg * 8];
                o[ni] = __builtin_amdgcn_mfma_f32_16x16x32_bf16(ah, bh, o[ni], 0, 0, 0);
                o[ni] = __builtin_amdgcn_mfma_f32_16x16x32_bf16(ah, bl, o[ni], 0, 0, 0);
                o[ni] = __builtin_amdgcn_mfma_f32_16x16x32_bf16(al, bh, o[ni], 0, 0, 0);
            }
        }
    }

    #pragma unroll
    for (int i = 0; i < 4; i++) {
        float inv = 1.0f / lrun[i];
        #pragma unroll
        for (int ni = 0; ni < 4; ni++) o[ni][i] *= inv;
    }
    #pragma unroll
    for (int ni = 0; ni < 4; ni++) {
        int col = hcol + ni * 16 + l15;
        #pragma unroll
        for (int i = 0; i < 4; i++) {
            int row = q0 + w * 16 + lg * 4 + i;
            size_t idx = (size_t)row * D_DIM + col;
            float v = o[ni][i];
            ushort_t hp = f2bf(v);
            chi[idx] = hp;
            clo[idx] = f2bf(v - bf2f(hp));
        }
    }
}

// ---------------- head ----------------
__global__ __launch_bounds__(256) void head_kernel(const float* __restrict__ x,
                                                   const float* __restrict__ lnf,
                                                   const float* __restrict__ E,
                                                   const int* __restrict__ tok,
                                                   float* __restrict__ soft) {
    int t = blockIdx.x;
    int tid = threadIdx.x;
    __shared__ float y[D_DIM];
    __shared__ float red[4];
    __shared__ float logits[V_DIM];
    const float* xr = x + (size_t)t * D_DIM;
    float ss = 0.f;
    for (int d = tid; d < D_DIM; d += 256) { float v = xr[d]; ss += v * v; }
    int lane = tid & 63, wave = tid >> 6;
    for (int off = 32; off > 0; off >>= 1) ss += __shfl_xor(ss, off);
    if (lane == 0) red[wave] = ss;
    __syncthreads();
    ss = red[0] + red[1] + red[2] + red[3];
    float r = 1.0f / sqrtf(ss * (1.0f / D_DIM) + 1e-6f);
    for (int d = tid; d < D_DIM; d += 256) y[d] = xr[d] * r * lnf[d];
    __syncthreads();
    for (int vv = wave; vv < V_DIM; vv += 4) {
        float p = 0.f;
        for (int d = lane; d < D_DIM; d += 64) p += y[d] * E[vv * D_DIM + d];
        for (int off = 32; off > 0; off >>= 1) p += __shfl_xor(p, off);
        if (lane == 0) logits[vv] = p;
    }
    __syncthreads();
    if (tid == 0) {
        int tk = tok[t];
        if (tk != MASK_ID) {
            for (int vv = 0; vv < V_DIM; vv++) soft[t * V_DIM + vv] = (vv == tk) ? 1.f : 0.f;
        } else {
            float mx = -1e30f;
            for (int vv = 0; vv < V_DIM; vv++) mx = fmaxf(mx, logits[vv]);
            float sm = 0.f;
            float e[V_DIM];
            for (int vv = 0; vv < V_DIM; vv++) { e[vv] = expf(logits[vv] - mx); sm += e[vv]; }
            float invs = 1.0f / sm;
            for (int vv = 0; vv < V_DIM; vv++) soft[t * V_DIM + vv] = e[vv] * invs;
        }
    }
}

// ---------------- argmax ----------------
__global__ void argmax_kernel(const float* __restrict__ soft, int* __restrict__ out) {
    int t = blockIdx.x * blockDim.x + threadIdx.x;
    if (t < T_LEN) {
        const float* s = soft + t * V_DIM;
        int best = 0;
        float bv = s[0];
        #pragma unroll
        for (int vv = 1; vv < V_DIM; vv++) {
            float v = s[vv];
            if (v > bv) { bv = v; best = vv; }
        }
        out[t] = best;
    }
}

// ================= fallback kernels (fp32, if ws too small) =================
__global__ __launch_bounds__(256) void rms_kernel(const float* __restrict__ x,
                                                  const float* __restrict__ w,
                                                  float* __restrict__ out) {
    int t = blockIdx.x;
    const float* xr = x + (size_t)t * D_DIM;
    float ss = 0.f;
    for (int d = threadIdx.x; d < D_DIM; d += 256) { float v = xr[d]; ss += v * v; }
    __shared__ float red[4];
    int lane = threadIdx.x & 63, wave = threadIdx.x >> 6;
    for (int off = 32; off > 0; off >>= 1) ss += __shfl_xor(ss, off);
    if (lane == 0) red[wave] = ss;
    __syncthreads();
    ss = red[0] + red[1] + red[2] + red[3];
    float r = 1.0f / sqrtf(ss * (1.0f / D_DIM) + 1e-6f);
    for (int d = threadIdx.x; d < D_DIM; d += 256) out[(size_t)t * D_DIM + d] = xr[d] * r * w[d];
}

__global__ __launch_bounds__(256) void embed_kernel(const float* __restrict__ soft,
                                                    const float* __restrict__ E,
                                                    float* __restrict__ x) {
    int t = blockIdx.x;
    __shared__ float srow[V_DIM];
    if (threadIdx.x < V_DIM) srow[threadIdx.x] = soft[t * V_DIM + threadIdx.x];
    __syncthreads();
    for (int d = threadIdx.x; d < D_DIM; d += 256) {
        float acc = 0.f;
        #pragma unroll
        for (int v = 0; v < V_DIM; v++) acc += srow[v] * E[v * D_DIM + d];
        x[(size_t)t * D_DIM + d] = acc;
    }
}

__global__ __launch_bounds__(256) void gemm_kernel(const float* __restrict__ A,
                                                   const float* __restrict__ B,
                                                   float* __restrict__ C,
                                                   int M, int N, int K,
                                                   float alpha, int accumulate) {
    const int BM = 64, BN = 64, BK = 16;
    __shared__ float As[BK][BM];
    __shared__ float Bsh[BK][BN];
    int tid = threadIdx.x;
    int tx = tid % 16, ty = tid / 16;
    int row0 = blockIdx.y * BM, col0 = blockIdx.x * BN;
    float acc[4][4] = {};
    for (int k0 = 0; k0 < K; k0 += BK) {
        #pragma unroll
        for (int i = 0; i < 4; i++) {
            int e = tid * 4 + i;
            int m = e / BK, kk = e % BK;
            int gr = row0 + m, gk = k0 + kk;
            As[kk][m] = (gr < M && gk < K) ? A[(size_t)gr * K + gk] : 0.f;
        }
        #pragma unroll
        for (int i = 0; i < 4; i++) {
            int e = tid * 4 + i;
            int kk = e / BN, n = e % BN;
            int gk = k0 + kk, gc = col0 + n;
            Bsh[kk][n] = (gk < K && gc < N) ? B[(size_t)gk * N + gc] : 0.f;
        }
        __syncthreads();
        #pragma unroll
        for (int kk = 0; kk < BK; kk++) {
            float a[4], b[4];
            #pragma unroll
            for (int i = 0; i < 4; i++) a[i] = As[kk][ty * 4 + i];
            #pragma unroll
            for (int j = 0; j < 4; j++) b[j] = Bsh[kk][tx * 4 + j];
            #pragma unroll
            for (int i = 0; i < 4; i++)
                #pragma unroll
                for (int j = 0; j < 4; j++)
                    acc[i][j] += a[i] * b[j];
        }
        __syncthreads();
    }
    #pragma unroll
    for (int i = 0; i < 4; i++) {
        int r = row0 + ty * 4 + i;
        if (r >= M) continue;
        #pragma unroll
        for (int j = 0; j < 4; j++) {
            int c = col0 + tx * 4 + j;
            if (c >= N) continue;
            size_t idx = (size_t)r * N + c;
            float val = alpha * acc[i][j];
            if (accumulate) val += C[idx];
            C[idx] = val;
        }
    }
}

__global__ __launch_bounds__(256) void attn_kernel(const float* __restrict__ q,
                                                   const float* __restrict__ k,
                                                   const float* __restrict__ v,
                                                   float* __restrict__ ctx) {
    int qi = blockIdx.x;
    int hh = blockIdx.y;
    __shared__ float sc[T_LEN];
    __shared__ float qrow[DH_DIM];
    __shared__ float red[8];
    __shared__ float part[4][DH_DIM];
    int tid = threadIdx.x;
    int lane = tid & 63, wave = tid >> 6;
    const float* qp = q + (size_t)qi * D_DIM + hh * DH_DIM;
    if (tid < DH_DIM) qrow[tid] = qp[tid];
    __syncthreads();
    const float scale = 0.125f;
    for (int j = wave; j <= qi; j += 4) {
        const float* kp = k + (size_t)j * D_DIM + hh * DH_DIM;
        float p = qrow[lane] * kp[lane];
        for (int off = 32; off > 0; off >>= 1) p += __shfl_xor(p, off);
        if (lane == 0) sc[j] = p * scale;
    }
    __syncthreads();
    int n = qi + 1;
    float m = -1e30f;
    for (int j = tid; j < n; j += 256) m = fmaxf(m, sc[j]);
    for (int off = 32; off > 0; off >>= 1) m = fmaxf(m, __shfl_xor(m, off));
    if (lane == 0) red[wave] = m;
    __syncthreads();
    m = fmaxf(fmaxf(red[0], red[1]), fmaxf(red[2], red[3]));
    float s = 0.f;
    for (int j = tid; j < n; j += 256) { float e = expf(sc[j] - m); sc[j] = e; s += e; }
    for (int off = 32; off > 0; off >>= 1) s += __shfl_xor(s, off);
    if (lane == 0) red[4 + wave] = s;
    __syncthreads();
    s = red[4] + red[5] + red[6] + red[7];
    float inv = 1.0f / s;
    float acc = 0.f;
    for (int j = wave; j < n; j += 4) {
        acc += sc[j] * v[(size_t)j * D_DIM + hh * DH_DIM + lane];
    }
    part[wave][lane] = acc;
    __syncthreads();
    if (tid < DH_DIM) {
        float r = (part[0][tid] + part[1][tid] + part[2][tid] + part[3][tid]) * inv;
        ctx[(size_t)qi * D_DIM + hh * DH_DIM + tid] = r;
    }
}

__global__ void silu_mul_kernel(const float* __restrict__ g, const float* __restrict__ u,
                                float* __restrict__ out, int nelem) {
    int i = blockIdx.x * blockDim.x + threadIdx.x;
    if (i < nelem) {
        float gv = g[i];
        float sg = 1.0f / (1.0f + expf(-gv));
        out[i] = gv * sg * u[i];
    }
}

static inline void launch_gemm(const float* A, const float* B, float* C,
                               int M, int N, int K, float alpha, int accumulate,
                               hipStream_t stream) {
    dim3 grid((N + 63) / 64, (M + 63) / 64);
    gemm_kernel<<<grid, 256, 0, stream>>>(A, B, C, M, N, K, alpha, accumulate);
}

// =====================================================================================
extern "C" void kernel_launch(void* const* d_in, const int* in_sizes, int n_in,
                              void* d_out, int out_size, void* d_ws, size_t ws_size,
                              hipStream_t stream) {
    const int* packed = (const int*)d_in[0];
    const float* E  = (const float*)d_in[6];
    const float* Wsrc[7] = {(const float*)d_in[7],  (const float*)d_in[10], (const float*)d_in[13],
                            (const float*)d_in[16], (const float*)d_in[19], (const float*)d_in[22],
                            (const float*)d_in[25]};
    const float* Asrc[7] = {(const float*)d_in[8],  (const float*)d_in[11], (const float*)d_in[14],
                            (const float*)d_in[17], (const float*)d_in[20], (const float*)d_in[23],
                            (const float*)d_in[26]};
    const float* Bsrc[7] = {(const float*)d_in[9],  (const float*)d_in[12], (const float*)d_in[15],
                            (const float*)d_in[18], (const float*)d_in[21], (const float*)d_in[24],
                            (const float*)d_in[27]};
    const float* ln1 = (const float*)d_in[28];
    const float* ln2 = (const float*)d_in[29];
    const float* lnf = (const float*)d_in[30];

    const size_t DD = (size_t)D_DIM * D_DIM;     // 1M
    const size_t DF = (size_t)D_DIM * F_DIM;     // 4M
    const size_t wsizes[7] = {DD, DD, DD, DD, DF, DF, DF};
    const int Kdim[7] = {D_DIM, D_DIM, D_DIM, D_DIM, D_DIM, D_DIM, F_DIM};
    const int Ndim[7] = {D_DIM, D_DIM, D_DIM, D_DIM, F_DIM, F_DIM, D_DIM};

    size_t u16_elems = 0;
    for (int p = 0; p < 7; p++) u16_elems += 2ull * N_LAYERS * wsizes[p];  // folded hi/lo
    u16_elems += 2ull * DD;            // h hi/lo
    u16_elems += 2ull * DD;            // ctx hi/lo
    u16_elems += 2ull * DF;            // ff hi/lo
    u16_elems += 6ull * DD;            // q,k,v hi/lo
    size_t f32_elems = (size_t)T_LEN * V_DIM + DD + 8 * DD;   // soft, x, 8-slot pool
    size_t need = u16_elems * 2 + f32_elems * 4 + 256;

    if (ws_size >= need) {
        ushort_t* ub = (ushort_t*)d_ws;
        size_t uo = 0;
        ushort_t *Whi[7], *Wlo[7];
        for (int p = 0; p < 7; p++) {
            Whi[p] = ub + uo; uo += (size_t)N_LAYERS * wsizes[p];
            Wlo[p] = ub + uo; uo += (size_t)N_LAYERS * wsizes[p];
        }
        ushort_t* h_hi = ub + uo; uo += DD;
        ushort_t* h_lo = ub + uo; uo += DD;
        ushort_t* c_hi = ub + uo; uo += DD;
        ushort_t* c_lo = ub + uo; uo += DD;
        ushort_t* f_hi = ub + uo; uo += DF;
        ushort_t* f_lo = ub + uo; uo += DF;
        ushort_t* qbh = ub + uo; uo += DD;
        ushort_t* qbl = ub + uo; uo += DD;
        ushort_t* kbh = ub + uo; uo += DD;
        ushort_t* kbl = ub + uo; uo += DD;
        ushort_t* vbh = ub + uo; uo += DD;
        ushort_t* vbl = ub + uo; uo += DD;
        float* fb = (float*)(ub + uo);
        size_t fo = 0;
        float* soft = fb + fo; fo += (size_t)T_LEN * V_DIM;
        float* x    = fb + fo; fo += DD;
        float* P    = fb + fo;   // 8-slot DD pool (= 2 DF slots)

        // fold weights (batched over layers)
        for (int p = 0; p < 7; p++) {
            dim3 grid(Ndim[p] / 64, Kdim[p] / 64, N_LAYERS);
            fold_kernel<<<grid, 256, 0, stream>>>(Wsrc[p], Asrc[p], Bsrc[p],
                                                  Whi[p], Wlo[p], Kdim[p], Ndim[p]);
        }

        init_soft_kernel<<<(T_LEN * V_DIM + 255) / 256, 256, 0, stream>>>(soft);

        const int n4 = (int)(DD / 4);
        GemmJob jz = {};

        for (int step = 0; step < N_STEPS; step++) {
            embed_rms_split_kernel<<<T_LEN, 256, 0, stream>>>(soft, E, ln1, x, h_hi, h_lo);
            for (int l = 0; l < N_LAYERS; l++) {
                {   // fused QKV, split-K x2: 384 blocks, 16 k-iters each
                    GemmJob jq = {Whi[0] + l * DD, Wlo[0] + l * DD, P,          nullptr, nullptr, 0, D_DIM};
                    GemmJob jk = {Whi[1] + l * DD, Wlo[1] + l * DD, P + 2 * DD, nullptr, nullptr, 0, D_DIM};
                    GemmJob jv = {Whi[2] + l * DD, Wlo[2] + l * DD, P + 4 * DD, nullptr, nullptr, 0, D_DIM};
                    gemm128_kernel<<<dim3(8, 8, 6), 256, 0, stream>>>(
                        h_hi, h_lo, D_DIM, D_DIM, 2, jq, jk, jv, jz, jz, jz, jz, jz);
                    qkv_sum_split_kernel<<<(int)(DD / 4 / 256), 256, 0, stream>>>(
                        P, 2, qbh, qbl, kbh, kbl, vbh, vbl);
                }
                attn_mfma_kernel<<<dim3(T_LEN / 64, H_NUM), 256, 0, stream>>>(
                    qbh, qbl, kbh, kbl, vbh, vbl, c_hi, c_lo);
                {   // o-proj split-K x4 (256 blocks, 8 iters) + fused add + rms(ln2[l])
                    GemmJob jo = {Whi[3] + l * DD, Wlo[3] + l * DD, P, nullptr, nullptr, 0, D_DIM};
                    gemm128_kernel<<<dim3(8, 8, 4), 256, 0, stream>>>(
                        c_hi, c_lo, D_DIM, D_DIM, 4, jo, jz, jz, jz, jz, jz, jz, jz);
                    add_rms_split_kernel<<<T_LEN, 256, 0, stream>>>(
                        x, P, 4, ln2 + (size_t)l * D_DIM, h_hi, h_lo);
                }
                {   // G,U (512 blocks, 32 iters)
                    GemmJob jg = {Whi[4] + l * DF, Wlo[4] + l * DF, P,      nullptr, nullptr, 0, D_DIM};
                    GemmJob ju = {Whi[5] + l * DF, Wlo[5] + l * DF, P + DF, nullptr, nullptr, 0, D_DIM};
                    gemm128_kernel<<<dim3(32, 8, 2), 256, 0, stream>>>(
                        h_hi, h_lo, D_DIM, F_DIM, 1, jg, ju, jz, jz, jz, jz, jz, jz);
                    silu_sum_split_kernel<<<(int)(DF / 4 / 256), 256, 0, stream>>>(
                        P, 1, f_hi, f_lo);
                }
                {   // d-proj split-K x8 (512 blocks, 16 iters)
                    GemmJob jd = {Whi[6] + l * DF, Wlo[6] + l * DF, P, nullptr, nullptr, 0, F_DIM};
                    gemm128_kernel<<<dim3(8, 8, 8), 256, 0, stream>>>(
                        f_hi, f_lo, F_DIM, D_DIM, 8, jd, jz, jz, jz, jz, jz, jz, jz);
                    if (l + 1 < N_LAYERS) {
                        add_rms_split_kernel<<<T_LEN, 256, 0, stream>>>(
                            x, P, 8, ln1 + (size_t)(l + 1) * D_DIM, h_hi, h_lo);
                    } else {
                        addn_kernel<<<(n4 + 255) / 256, 256, 0, stream>>>(x, P, 8, n4);
                    }
                }
            }
            head_kernel<<<T_LEN, 256, 0, stream>>>(x, lnf, E, packed, soft);
        }
        argmax_kernel<<<(T_LEN + 255) / 256, 256, 0, stream>>>(soft, (int*)d_out);
        return;
    }

    // -------- fallback: fp32 path --------
    float* ws = (float*)d_ws;
    size_t off = 0;
    float* soft = ws + off; off += (size_t)T_LEN * V_DIM;
    float* x    = ws + off; off += (size_t)T_LEN * D_DIM;
    float* h    = ws + off; off += (size_t)T_LEN * D_DIM;
    float* qb   = ws + off; off += (size_t)T_LEN * D_DIM;
    float* kb   = ws + off; off += (size_t)T_LEN * D_DIM;
    float* vb   = ws + off; off += (size_t)T_LEN * D_DIM;
    float* cb   = ws + off; off += (size_t)T_LEN * D_DIM;
    float* gb   = ws + off; off += (size_t)T_LEN * F_DIM;
    float* ubf  = ws + off; off += (size_t)T_LEN * F_DIM;
    float* tmp  = ws + off; off += (size_t)T_LEN * R_LORA;

    init_soft_kernel<<<(T_LEN * V_DIM + 255) / 256, 256, 0, stream>>>(soft);
    for (int step = 0; step < N_STEPS; step++) {
        embed_kernel<<<T_LEN, 256, 0, stream>>>(soft, E, x);
        for (int l = 0; l < N_LAYERS; l++) {
            const float* ln1_l = ln1 + (size_t)l * D_DIM;
            const float* ln2_l = ln2 + (size_t)l * D_DIM;
            rms_kernel<<<T_LEN, 256, 0, stream>>>(x, ln1_l, h);
            launch_gemm(h, Asrc[0] + (size_t)l * D_DIM * R_LORA, tmp, T_LEN, R_LORA, D_DIM, 1.0f, 0, stream);
            launch_gemm(h, Wsrc[0] + (size_t)l * DD, qb, T_LEN, D_DIM, D_DIM, 1.0f, 0, stream);
            launch_gemm(tmp, Bsrc[0] + (size_t)l * R_LORA * D_DIM, qb, T_LEN, D_DIM, R_LORA, LORA_SCALE, 1, stream);
            launch_gemm(h, Asrc[1] + (size_t)l * D_DIM * R_LORA, tmp, T_LEN, R_LORA, D_DIM, 1.0f, 0, stream);
            launch_gemm(h, Wsrc[1] + (size_t)l * DD, kb, T_LEN, D_DIM, D_DIM, 1.0f, 0, stream);
            launch_gemm(tmp, Bsrc[1] + (size_t)l * R_LORA * D_DIM, kb, T_LEN, D_DIM, R_LORA, LORA_SCALE, 1, stream);
            launch_gemm(h, Asrc[2] + (size_t)l * D_DIM * R_LORA, tmp, T_LEN, R_LORA, D_DIM, 1.0f, 0, stream);
            launch_gemm(h, Wsrc[2] + (size_t)l * DD, vb, T_LEN, D_DIM, D_DIM, 1.0f, 0, stream);
            launch_gemm(tmp, Bsrc[2] + (size_t)l * R_LORA * D_DIM, vb, T_LEN, D_DIM, R_LORA, LORA_SCALE, 1, stream);
            attn_kernel<<<dim3(T_LEN, H_NUM), 256, 0, stream>>>(qb, kb, vb, cb);
            launch_gemm(cb, Asrc[3] + (size_t)l * D_DIM * R_LORA, tmp, T_LEN, R_LORA, D_DIM, 1.0f, 0, stream);
            launch_gemm(cb, Wsrc[3] + (size_t)l * DD, x, T_LEN, D_DIM, D_DIM, 1.0f, 1, stream);
            launch_gemm(tmp, Bsrc[3] + (size_t)l * R_LORA * D_DIM, x, T_LEN, D_DIM, R_LORA, LORA_SCALE, 1, stream);
            rms_kernel<<<T_LEN, 256, 0, stream>>>(x, ln2_l, h);
            launch_gemm(h, Asrc[4] + (size_t)l * D_DIM * R_LORA, tmp, T_LEN, R_LORA, D_DIM, 1.0f, 0, stream);
            launch_gemm(h, Wsrc[4] + (size_t)l * DF, gb, T_LEN, F_DIM, D_DIM, 1.0f, 0, stream);
            launch_gemm(tmp, Bsrc[4] + (size_t)l * R_LORA * F_DIM, gb, T_LEN, F_DIM, R_LORA, LORA_SCALE, 1, stream);
            launch_gemm(h, Asrc[5] + (size_t)l * D_DIM * R_LORA, tmp, T_LEN, R_LORA, D_DIM, 1.0f, 0, stream);
            launch_gemm(h, Wsrc[5] + (size_t)l * DF, ubf, T_LEN, F_DIM, D_DIM, 1.0f, 0, stream);
            launch_gemm(tmp, Bsrc[5] + (size_t)l * R_LORA * F_DIM, ubf, T_LEN, F_DIM, R_LORA, LORA_SCALE, 1, stream);
            silu_mul_kernel<<<(T_LEN * F_DIM + 255) / 256, 256, 0, stream>>>(gb, ubf, gb, T_LEN * F_DIM);
            launch_gemm(gb, Asrc[6] + (size_t)l * F_DIM * R_LORA, tmp, T_LEN, R_LORA, F_DIM, 1.0f, 0, stream);
            launch_gemm(gb, Wsrc[6] + (size_t)l * DF, x, T_LEN, D_DIM, F_DIM, 1.0f, 1, stream);
            launch_gemm(tmp, Bsrc[6] + (size_t)l * R_LORA * D_DIM, x, T_LEN, D_DIM, R_LORA, LORA_SCALE, 1, stream);
        }
        head_kernel<<<T_LEN, 256, 0, stream>>>(x, lnf, E, packed, soft);
    }
    argmax_kernel<<<(T_LEN + 255) / 256, 256, 0, stream>>>(soft, (int*)d_out);
}